// Round 4
// baseline (162.611 us; speedup 1.0000x reference)
//
#include <hip/hip_runtime.h>

#define TWOPI 6.28318530717958647692f

#define BB 2
#define CC 32
#define NN 8192
#define MH 864                      // 12*12*6 retained modes
#define XFT_FLOATS (BB*MH*CC*2)     // 110592
#define NCH 64                      // split-K chunks for forward

__device__ __forceinline__ float2 cmul(float2 a, float2 b){
    return make_float2(fmaf(a.x, b.x, -(a.y*b.y)), fmaf(a.x, b.y, a.y*b.x));
}

// ---------------- weight transpose: wt[q][abz][i][o][2] ----------------
__global__ __launch_bounds__(256)
void wtrans_kernel(const float* __restrict__ w1, const float* __restrict__ w2,
                   const float* __restrict__ w3, const float* __restrict__ w4,
                   float* __restrict__ wt){
    const int abz = blockIdx.x;       // 0..215  (a*36 + b*6 + z)
    const int q   = blockIdx.y;       // 0..3
    const float* w = (q==0)?w1:(q==1)?w2:(q==2)?w3:w4;
    const int tid = threadIdx.x;
    #pragma unroll
    for (int k=0;k<4;k++){
        int iop = tid + k*256;        // (i*32+o) in 0..1023
        float2 v = *(const float2*)(w + ((size_t)iop*216 + abz)*2);
        *(float2*)(wt + (((size_t)q*216 + abz)*1024 + iop)*2) = v;
    }
}

// ---------------- forward NUFFT: xft[b][m][c][2] (split-K partials) ----------------
// grid (NCH, 9, B), block 128 = 16 columns x 8 cslots(4 ch each)
template<bool ATOMIC>
__global__ __launch_bounds__(128, 2)
void fwd_kernel(const float* __restrict__ x, const float* __restrict__ pos,
                float* __restrict__ dst){
    const int tid = threadIdx.x;
    const int colslot = tid & 15;
    const int cs = tid >> 4;                  // 0..7
    const int col = blockIdx.y * 16 + colslot; // 0..143  (= ix*12 + iy)
    const int ixm = col / 12;
    const int iym = col % 12;
    const int b   = blockIdx.z;
    const int nch = blockIdx.x;
    const int nb0 = nch * (NN / NCH);         // chunk of 128 points

    __shared__ float2 exl[12][65];
    __shared__ float2 eyl[12][65];
    __shared__ float2 ezt[64][8];
    __shared__ float  xl[CC][68];

    float acc[6][4][2];
    #pragma unroll
    for (int z=0;z<6;z++)
      #pragma unroll
      for (int j=0;j<4;j++){ acc[z][j][0]=0.f; acc[z][j][1]=0.f; }

    for (int t=0; t<2; ++t){
        const int nb = nb0 + t*64;
        __syncthreads();
        if (tid < 64){
            const int n = nb + tid;
            const float px = pos[((size_t)b*NN + n)*3 + 0];
            const float py = pos[((size_t)b*NN + n)*3 + 1];
            const float pz = pos[((size_t)b*NN + n)*3 + 2];
            float s, c;
            float2 pw[7];
            // forward phase: exp(-i*2pi*k*p); e1 = exp(-i*2pi*p)
            sincosf(TWOPI*px, &s, &c);
            { float2 e1 = make_float2(c, -s);
              pw[0] = make_float2(1.f, 0.f);
              #pragma unroll
              for (int k=1;k<7;k++) pw[k] = cmul(pw[k-1], e1);
              #pragma unroll
              for (int k=0;k<6;k++) exl[k][tid] = pw[k];
              #pragma unroll
              for (int k=6;k<12;k++) exl[k][tid] = make_float2(pw[12-k].x, -pw[12-k].y);
            }
            sincosf(TWOPI*py, &s, &c);
            { float2 e1 = make_float2(c, -s);
              pw[0] = make_float2(1.f, 0.f);
              #pragma unroll
              for (int k=1;k<7;k++) pw[k] = cmul(pw[k-1], e1);
              #pragma unroll
              for (int k=0;k<6;k++) eyl[k][tid] = pw[k];
              #pragma unroll
              for (int k=6;k<12;k++) eyl[k][tid] = make_float2(pw[12-k].x, -pw[12-k].y);
            }
            sincosf(TWOPI*pz, &s, &c);
            { float2 e1 = make_float2(c, -s);
              float2 qv = make_float2(1.f, 0.f);
              #pragma unroll
              for (int k=0;k<6;k++){ ezt[tid][k] = qv; qv = cmul(qv, e1); }
            }
        }
        #pragma unroll
        for (int k=0;k<4;k++){
            int v = tid + k*128;
            int c = v >> 4;
            int j = v & 15;
            float4 xv = *(const float4*)(x + (size_t)(b*CC + c)*NN + nb + j*4);
            *(float4*)(&xl[c][j*4]) = xv;
        }
        __syncthreads();

        #pragma unroll 2
        for (int np=0; np<64; ++np){
            float2 rex = exl[ixm][np];
            float2 rey = eyl[iym][np];
            float2 exy = cmul(rex, rey);
            float xv0 = xl[cs*4+0][np];
            float xv1 = xl[cs*4+1][np];
            float xv2 = xl[cs*4+2][np];
            float xv3 = xl[cs*4+3][np];
            const float4* ezp = (const float4*)(&ezt[np][0]);
            float4 ea = ezp[0], eb2 = ezp[1], ec = ezp[2];
            float2 ezv[6];
            ezv[0] = make_float2(ea.x, ea.y);  ezv[1] = make_float2(ea.z, ea.w);
            ezv[2] = make_float2(eb2.x, eb2.y); ezv[3] = make_float2(eb2.z, eb2.w);
            ezv[4] = make_float2(ec.x, ec.y);  ezv[5] = make_float2(ec.z, ec.w);
            #pragma unroll
            for (int z=0; z<6; ++z){
                float2 ph = cmul(exy, ezv[z]);
                acc[z][0][0] = fmaf(ph.x, xv0, acc[z][0][0]);
                acc[z][0][1] = fmaf(ph.y, xv0, acc[z][0][1]);
                acc[z][1][0] = fmaf(ph.x, xv1, acc[z][1][0]);
                acc[z][1][1] = fmaf(ph.y, xv1, acc[z][1][1]);
                acc[z][2][0] = fmaf(ph.x, xv2, acc[z][2][0]);
                acc[z][2][1] = fmaf(ph.y, xv2, acc[z][2][1]);
                acc[z][3][0] = fmaf(ph.x, xv3, acc[z][3][0]);
                acc[z][3][1] = fmaf(ph.y, xv3, acc[z][3][1]);
            }
        }
    }

    const int c0 = cs*4;
    if (ATOMIC){
        #pragma unroll
        for (int z=0;z<6;z++)
          #pragma unroll
          for (int j=0;j<4;j++){
            float* p = dst + (((size_t)b*MH + col*6 + z)*CC + c0 + j)*2;
            atomicAdd(p+0, acc[z][j][0]);
            atomicAdd(p+1, acc[z][j][1]);
          }
    } else {
        float* base = dst + (size_t)nch*XFT_FLOATS;
        #pragma unroll
        for (int z=0;z<6;z++)
          #pragma unroll
          for (int j=0;j<4;j++){
            *(float2*)(base + (((size_t)b*MH + col*6 + z)*CC + c0 + j)*2)
                = make_float2(acc[z][j][0], acc[z][j][1]);
          }
    }
}

// ---------------- split-K reduce ----------------
__global__ __launch_bounds__(256)
void reduce_kernel(const float* __restrict__ part, float* __restrict__ xft){
    const int i = blockIdx.x*256 + threadIdx.x;   // 110592 = 432*256
    float s = 0.f;
    #pragma unroll 8
    for (int k=0;k<NCH;k++) s += part[(size_t)k*XFT_FLOATS + i];
    xft[i] = s;
}

// ---------------- spectral mix + hermitian channel fold: T[b][m][c<16][2] ----------------
// grid (108, B), block 256 = 8 modes x 32 out-channels
__global__ __launch_bounds__(256)
void mix_kernel(const float* __restrict__ xft, const float* __restrict__ wt,
                float* __restrict__ T){
    const int tid = threadIdx.x;
    const int o  = tid & 31;
    const int ml = tid >> 5;      // 0..7
    const int b  = blockIdx.y;
    const int m0 = blockIdx.x * 8;

    __shared__ float xs[512];
    __shared__ float os[8][32][2];

    const float* xb = xft + ((size_t)b*MH + m0)*64;
    xs[tid]     = xb[tid];
    xs[tid+256] = xb[tid+256];
    __syncthreads();

    const int m  = m0 + ml;
    const int ix = m / 72;
    const int iy = (m / 6) % 12;
    const int iz = m % 6;
    const int q  = (ix>=6 ? 1 : 0) + (iy>=6 ? 2 : 0);   // w1,w2,w3,w4
    const int a  = ix % 6;
    const int bb2 = iy % 6;
    const int abz = (a*6 + bb2)*6 + iz;
    const float* wq = wt + ((size_t)q*216 + abz)*2048;

    float orr = 0.f, oii = 0.f;
    #pragma unroll 8
    for (int i=0;i<32;i++){
        float xr = xs[ml*64 + i*2];
        float xi = xs[ml*64 + i*2 + 1];
        float2 wv = *(const float2*)(wq + (i*32 + o)*2);
        orr = fmaf(xr, wv.x, orr); orr = fmaf(-xi, wv.y, orr);
        oii = fmaf(xr, wv.y, oii); oii = fmaf( xi, wv.x, oii);
    }
    os[ml][o][0] = orr;
    os[ml][o][1] = oii;
    __syncthreads();
    if (o < 16){
        float tr = os[ml][o][0] + os[ml][31-o][0];
        float ti = os[ml][o][1] + os[ml][31-o][1];
        *(float2*)(T + (((size_t)b*MH + m)*16 + o)*2) = make_float2(tr, ti);
    }
}

// ---------------- inverse NUFFT (no atomics, 4-deep register prefetch ring) ----------------
// y[b][c][n] = y[b][31-c][n] = (2/N)*Re sum_m ph[m,n]*T[m,c]
// grid (NN/64, B), block 512 = 8 waves x 64 n-lanes. Wave w owns 18 (ix,iy) pairs,
// whose T data is one LINEAR run of 108 x 128B blocks -> 4-deep prefetch ring.
__global__ __launch_bounds__(512, 2)
void inv_kernel(const float* __restrict__ pos, const float* __restrict__ T,
                float* __restrict__ y){
    const int tid = threadIdx.x;
    const int nl  = tid & 63;
    const int b   = blockIdx.y;
    const int n0  = blockIdx.x * 64;

    __shared__ float2 exl[12][64];
    __shared__ float2 eyl[12][64];
    __shared__ float2 ezl[6][64];
    __shared__ float  red[8][16][64];

    const int wv = tid >> 6;
    if (wv < 3){
        // wave wv builds the phase table for axis wv (x:0 y:1 z:2)
        const int n = n0 + nl;
        const float pc = pos[((size_t)b*NN + n)*3 + wv];
        float s, c;
        sincosf(TWOPI*pc, &s, &c);
        float2 e1 = make_float2(c, s);          // exp(+i*2pi*p)
        float2 pw[7];
        pw[0] = make_float2(1.f, 0.f);
        #pragma unroll
        for (int k=1;k<7;k++) pw[k] = cmul(pw[k-1], e1);
        if (wv == 0){
            #pragma unroll
            for (int k=0;k<6;k++) exl[k][nl] = pw[k];
            #pragma unroll
            for (int k=6;k<12;k++) exl[k][nl] = make_float2(pw[12-k].x, -pw[12-k].y);
        } else if (wv == 1){
            #pragma unroll
            for (int k=0;k<6;k++) eyl[k][nl] = pw[k];
            #pragma unroll
            for (int k=6;k<12;k++) eyl[k][nl] = make_float2(pw[12-k].x, -pw[12-k].y);
        } else {
            #pragma unroll
            for (int k=0;k<6;k++) ezl[k][nl] = pw[k];
        }
    }
    __syncthreads();

    const int w = __builtin_amdgcn_readfirstlane(tid >> 6);   // wave id, uniform
    float acc[16];
    #pragma unroll
    for (int c=0;c<16;c++) acc[c] = 0.f;

    // wave's T region: 18 pairs * 6 iz * 32 floats = 3456 floats = 108 blocks of 8 float4
    const float4* tw = (const float4*)(T + (size_t)b*MH*32 + (size_t)w*3456);
    float4 buf[4][8];
    #pragma unroll
    for (int k=0;k<4;k++)
      #pragma unroll
      for (int i=0;i<8;i++) buf[k][i] = tw[k*8 + i];

// stage s (0..11): consume block (pq*12+s), prefetch block (pq*12+s+4)
#define STAGE(s) {                                                            \
    constexpr int iz_ = (s) % 6;                                              \
    if (iz_ == 0) exy = cmul(exl[((s)<6)?ix0:ix1][nl],                        \
                             eyl[((s)<6)?iy0:iy1][nl]);                       \
    float2 ph = cmul(exy, ezl[iz_][nl]);                                      \
    _Pragma("unroll")                                                         \
    for (int q=0;q<8;q++){                                                    \
        float4 tv = buf[(s)&3][q];                                            \
        acc[2*q]   = fmaf(ph.x, tv.x, fmaf(-ph.y, tv.y, acc[2*q]));           \
        acc[2*q+1] = fmaf(ph.x, tv.z, fmaf(-ph.y, tv.w, acc[2*q+1]));         \
    }                                                                         \
    const int g4 = (pq*12 + (s) + 4 < 108) ? (pq*12 + (s) + 4) : 107;         \
    _Pragma("unroll")                                                         \
    for (int i=0;i<8;i++) buf[(s)&3][i] = tw[(size_t)g4*8 + i];               \
}

    #pragma unroll 1
    for (int pq=0; pq<9; ++pq){
        const int pp0 = w*18 + pq*2;          // wave-uniform
        const int ix0 = pp0/12,     iy0 = pp0%12;
        const int ix1 = (pp0+1)/12, iy1 = (pp0+1)%12;
        float2 exy;
        STAGE(0)  STAGE(1)  STAGE(2)  STAGE(3)  STAGE(4)  STAGE(5)
        STAGE(6)  STAGE(7)  STAGE(8)  STAGE(9)  STAGE(10) STAGE(11)
    }
#undef STAGE

    #pragma unroll
    for (int c=0;c<16;c++) red[w][c][nl] = acc[c];
    __syncthreads();

    const float sc2 = 2.0f / (float)NN;
    #pragma unroll
    for (int t=0;t<2;t++){
        int oidx = tid + t*512;             // 0..1023 = c*64 + nn
        int c  = oidx >> 6;                 // 0..15
        int nn = oidx & 63;
        float s = 0.f;
        #pragma unroll
        for (int w2=0; w2<8; ++w2) s += red[w2][c][nn];
        s *= sc2;
        y[(size_t)b*CC*NN + (size_t)c*NN + n0 + nn]      = s;
        y[(size_t)b*CC*NN + (size_t)(31-c)*NN + n0 + nn] = s;
    }
}

extern "C" void kernel_launch(void* const* d_in, const int* in_sizes, int n_in,
                              void* d_out, int out_size, void* d_ws, size_t ws_size,
                              hipStream_t stream){
    const float* x   = (const float*)d_in[0];
    const float* pos = (const float*)d_in[1];
    const float* w1  = (const float*)d_in[2];
    const float* w2  = (const float*)d_in[3];
    const float* w3  = (const float*)d_in[4];
    const float* w4  = (const float*)d_in[5];
    float* out = (float*)d_out;
    char* wsb = (char*)d_ws;

    // ws layout (bytes):
    float* wt   = (float*)(wsb);                 // 4*216*1024*2*4 = 7,077,888
    float* xft  = (float*)(wsb + 7077888);       // 110592*4      =   442,368
    float* T    = (float*)(wsb + 7520256);       // 2*864*16*2*4  =   221,184
    float* part = (float*)(wsb + 7741440);       // 64*110592*4   = 28,311,552 (fwd partials)
    const bool use_part = (ws_size >= 36052992ull);

    wtrans_kernel<<<dim3(216,4), 256, 0, stream>>>(w1, w2, w3, w4, wt);

    if (use_part){
        fwd_kernel<false><<<dim3(NCH,9,2), 128, 0, stream>>>(x, pos, part);
        reduce_kernel<<<dim3(432), 256, 0, stream>>>(part, xft);
    } else {
        hipMemsetAsync(xft, 0, 442368, stream);
        fwd_kernel<true><<<dim3(NCH,9,2), 128, 0, stream>>>(x, pos, xft);
    }

    mix_kernel<<<dim3(108,2), 256, 0, stream>>>(xft, wt, T);

    inv_kernel<<<dim3(NN/64, BB), 512, 0, stream>>>(pos, T, out);
}

// Round 5
// 83.515 us; speedup vs baseline: 1.9471x; 1.9471x over previous
//
#include <hip/hip_runtime.h>
#include <hip/hip_bf16.h>

#define TWOPI 6.28318530717958647692f

#define BB 2
#define CC 32
#define NN 8192
#define MH 864                      // 12*12*6 retained modes
#define XFT_FLOATS (BB*MH*CC*2)     // 110592
#define NCH 64                      // split-K chunks for forward

typedef short bf16x8 __attribute__((ext_vector_type(8)));
typedef float f32x4  __attribute__((ext_vector_type(4)));

__device__ __forceinline__ float2 cmul(float2 a, float2 b){
    return make_float2(fmaf(a.x, b.x, -(a.y*b.y)), fmaf(a.x, b.y, a.y*b.x));
}
__device__ __forceinline__ float2 conj2(float2 a){ return make_float2(a.x, -a.y); }
__device__ __forceinline__ short f2bf(float x){
    __hip_bfloat16 h = __float2bfloat16(x);
    union { __hip_bfloat16 h; short s; } u; u.h = h; return u.s;
}

// ---------------- weight transpose: wt[q][abz][i][o][2] ----------------
__global__ __launch_bounds__(256)
void wtrans_kernel(const float* __restrict__ w1, const float* __restrict__ w2,
                   const float* __restrict__ w3, const float* __restrict__ w4,
                   float* __restrict__ wt){
    const int abz = blockIdx.x;       // 0..215  (a*36 + b*6 + z)
    const int q   = blockIdx.y;       // 0..3
    const float* w = (q==0)?w1:(q==1)?w2:(q==2)?w3:w4;
    const int tid = threadIdx.x;
    #pragma unroll
    for (int k=0;k<4;k++){
        int iop = tid + k*256;        // (i*32+o) in 0..1023
        float2 v = *(const float2*)(w + ((size_t)iop*216 + abz)*2);
        *(float2*)(wt + (((size_t)q*216 + abz)*1024 + iop)*2) = v;
    }
}

// ---------------- forward NUFFT: xft[b][m][c][2] (split-K partials) ----------------
// grid (NCH, 9, B), block 128 = 16 columns x 8 cslots(4 ch each)
template<bool ATOMIC>
__global__ __launch_bounds__(128, 2)
void fwd_kernel(const float* __restrict__ x, const float* __restrict__ pos,
                float* __restrict__ dst){
    const int tid = threadIdx.x;
    const int colslot = tid & 15;
    const int cs = tid >> 4;                  // 0..7
    const int col = blockIdx.y * 16 + colslot; // 0..143  (= ix*12 + iy)
    const int ixm = col / 12;
    const int iym = col % 12;
    const int b   = blockIdx.z;
    const int nch = blockIdx.x;
    const int nb0 = nch * (NN / NCH);         // chunk of 128 points

    __shared__ float2 exl[12][65];
    __shared__ float2 eyl[12][65];
    __shared__ float2 ezt[64][8];
    __shared__ float  xl[CC][68];

    float acc[6][4][2];
    #pragma unroll
    for (int z=0;z<6;z++)
      #pragma unroll
      for (int j=0;j<4;j++){ acc[z][j][0]=0.f; acc[z][j][1]=0.f; }

    for (int t=0; t<2; ++t){
        const int nb = nb0 + t*64;
        __syncthreads();
        if (tid < 64){
            const int n = nb + tid;
            const float px = pos[((size_t)b*NN + n)*3 + 0];
            const float py = pos[((size_t)b*NN + n)*3 + 1];
            const float pz = pos[((size_t)b*NN + n)*3 + 2];
            float s, c;
            float2 pw[7];
            // forward phase: exp(-i*2pi*k*p); e1 = exp(-i*2pi*p)
            sincosf(TWOPI*px, &s, &c);
            { float2 e1 = make_float2(c, -s);
              pw[0] = make_float2(1.f, 0.f);
              #pragma unroll
              for (int k=1;k<7;k++) pw[k] = cmul(pw[k-1], e1);
              #pragma unroll
              for (int k=0;k<6;k++) exl[k][tid] = pw[k];
              #pragma unroll
              for (int k=6;k<12;k++) exl[k][tid] = make_float2(pw[12-k].x, -pw[12-k].y);
            }
            sincosf(TWOPI*py, &s, &c);
            { float2 e1 = make_float2(c, -s);
              pw[0] = make_float2(1.f, 0.f);
              #pragma unroll
              for (int k=1;k<7;k++) pw[k] = cmul(pw[k-1], e1);
              #pragma unroll
              for (int k=0;k<6;k++) eyl[k][tid] = pw[k];
              #pragma unroll
              for (int k=6;k<12;k++) eyl[k][tid] = make_float2(pw[12-k].x, -pw[12-k].y);
            }
            sincosf(TWOPI*pz, &s, &c);
            { float2 e1 = make_float2(c, -s);
              float2 qv = make_float2(1.f, 0.f);
              #pragma unroll
              for (int k=0;k<6;k++){ ezt[tid][k] = qv; qv = cmul(qv, e1); }
            }
        }
        #pragma unroll
        for (int k=0;k<4;k++){
            int v = tid + k*128;
            int c = v >> 4;
            int j = v & 15;
            float4 xv = *(const float4*)(x + (size_t)(b*CC + c)*NN + nb + j*4);
            *(float4*)(&xl[c][j*4]) = xv;
        }
        __syncthreads();

        #pragma unroll 2
        for (int np=0; np<64; ++np){
            float2 rex = exl[ixm][np];
            float2 rey = eyl[iym][np];
            float2 exy = cmul(rex, rey);
            float xv0 = xl[cs*4+0][np];
            float xv1 = xl[cs*4+1][np];
            float xv2 = xl[cs*4+2][np];
            float xv3 = xl[cs*4+3][np];
            const float4* ezp = (const float4*)(&ezt[np][0]);
            float4 ea = ezp[0], eb2 = ezp[1], ec = ezp[2];
            float2 ezv[6];
            ezv[0] = make_float2(ea.x, ea.y);  ezv[1] = make_float2(ea.z, ea.w);
            ezv[2] = make_float2(eb2.x, eb2.y); ezv[3] = make_float2(eb2.z, eb2.w);
            ezv[4] = make_float2(ec.x, ec.y);  ezv[5] = make_float2(ec.z, ec.w);
            #pragma unroll
            for (int z=0; z<6; ++z){
                float2 ph = cmul(exy, ezv[z]);
                acc[z][0][0] = fmaf(ph.x, xv0, acc[z][0][0]);
                acc[z][0][1] = fmaf(ph.y, xv0, acc[z][0][1]);
                acc[z][1][0] = fmaf(ph.x, xv1, acc[z][1][0]);
                acc[z][1][1] = fmaf(ph.y, xv1, acc[z][1][1]);
                acc[z][2][0] = fmaf(ph.x, xv2, acc[z][2][0]);
                acc[z][2][1] = fmaf(ph.y, xv2, acc[z][2][1]);
                acc[z][3][0] = fmaf(ph.x, xv3, acc[z][3][0]);
                acc[z][3][1] = fmaf(ph.y, xv3, acc[z][3][1]);
            }
        }
    }

    const int c0 = cs*4;
    if (ATOMIC){
        #pragma unroll
        for (int z=0;z<6;z++)
          #pragma unroll
          for (int j=0;j<4;j++){
            float* p = dst + (((size_t)b*MH + col*6 + z)*CC + c0 + j)*2;
            atomicAdd(p+0, acc[z][j][0]);
            atomicAdd(p+1, acc[z][j][1]);
          }
    } else {
        float* base = dst + (size_t)nch*XFT_FLOATS;
        #pragma unroll
        for (int z=0;z<6;z++)
          #pragma unroll
          for (int j=0;j<4;j++){
            *(float2*)(base + (((size_t)b*MH + col*6 + z)*CC + c0 + j)*2)
                = make_float2(acc[z][j][0], acc[z][j][1]);
          }
    }
}

// ---------------- split-K reduce ----------------
__global__ __launch_bounds__(256)
void reduce_kernel(const float* __restrict__ part, float* __restrict__ xft){
    const int i = blockIdx.x*256 + threadIdx.x;   // 110592 = 432*256
    float s = 0.f;
    #pragma unroll 8
    for (int k=0;k<NCH;k++) s += part[(size_t)k*XFT_FLOATS + i];
    xft[i] = s;
}

// ---------------- spectral mix + hermitian channel fold -> bf16 A-matrix ----------------
// Abf fragment layout: slot(c, kk, c4, j) at ((c*54+kk)*4+c4)*8+j  holds
//   A[m = 216*c4 + 4*kk + (j>>1)][reim = j&1][c],
//   A[2m] = (2/N)*T.re, A[2m+1] = -(2/N)*T.im  (T = folded mixed spectrum)
// grid (108, B), block 256 = 8 modes x 32 out-channels
__global__ __launch_bounds__(256)
void mix_kernel(const float* __restrict__ xft, const float* __restrict__ wt,
                short* __restrict__ Abf){
    const int tid = threadIdx.x;
    const int o  = tid & 31;
    const int ml = tid >> 5;      // 0..7
    const int b  = blockIdx.y;
    const int m0 = blockIdx.x * 8;

    __shared__ float xs[512];
    __shared__ float os[8][32][2];

    const float* xb = xft + ((size_t)b*MH + m0)*64;
    xs[tid]     = xb[tid];
    xs[tid+256] = xb[tid+256];
    __syncthreads();

    const int m  = m0 + ml;
    const int ix = m / 72;
    const int iy = (m / 6) % 12;
    const int iz = m % 6;
    const int q  = (ix>=6 ? 1 : 0) + (iy>=6 ? 2 : 0);   // w1,w2,w3,w4
    const int a  = ix % 6;
    const int bb2 = iy % 6;
    const int abz = (a*6 + bb2)*6 + iz;
    const float* wq = wt + ((size_t)q*216 + abz)*2048;

    float orr = 0.f, oii = 0.f;
    #pragma unroll 8
    for (int i=0;i<32;i++){
        float xr = xs[ml*64 + i*2];
        float xi = xs[ml*64 + i*2 + 1];
        float2 wv = *(const float2*)(wq + (i*32 + o)*2);
        orr = fmaf(xr, wv.x, orr); orr = fmaf(-xi, wv.y, orr);
        oii = fmaf(xr, wv.y, oii); oii = fmaf( xi, wv.x, oii);
    }
    os[ml][o][0] = orr;
    os[ml][o][1] = oii;
    __syncthreads();
    if (o < 16){
        const float sc2 = 2.0f / (float)NN;
        float tr =  (os[ml][o][0] + os[ml][31-o][0]) * sc2;
        float ti = -((os[ml][o][1] + os[ml][31-o][1]) * sc2);
        const int mc4 = m / 216;
        const int mr  = m % 216;
        const int kk  = mr >> 2;
        const int qq  = mr & 3;
        short2 v; v.x = f2bf(tr); v.y = f2bf(ti);
        *(short2*)(Abf + (size_t)b*27648 + (((size_t)o*54 + kk)*4 + mc4)*8 + 2*qq) = v;
    }
}

// ---------------- inverse NUFFT: MFMA over K=1728 (864 modes x re/im) ----------------
// y[b][c][n] = y[b][31-c][n] = sum_k A[k][c] * P[k][n]
// grid (NN/64, B), block 256 = 4 waves; wave w owns n-tile n0+w*16.
// Phase operand P generated per-lane by a complex recurrence over the lane's
// CONTIGUOUS mode range m = 216*c4 + [0,216): one cmul per mode, factor chosen
// at compile time (iz-step Ez; wraps Cy/Cy6/Cx). No LDS, no atomics.
__global__ __launch_bounds__(256)
void inv_kernel(const float* __restrict__ pos, const short* __restrict__ Abf,
                float* __restrict__ y){
    const int tid = threadIdx.x;
    const int l   = tid & 63;
    const int w   = tid >> 6;            // wave 0..3 -> n-tile
    const int col = l & 15;              // B-col (n-offset) AND A-row (channel)
    const int c4  = l >> 4;              // k-slot group
    const int b   = blockIdx.y;
    const int n   = blockIdx.x*64 + w*16 + col;

    const float px = pos[((size_t)b*NN + n)*3 + 0];
    const float py = pos[((size_t)b*NN + n)*3 + 1];
    const float pz = pos[((size_t)b*NN + n)*3 + 2];
    float s, c;
    sincosf(TWOPI*px, &s, &c); const float2 Ex = make_float2(c, s);
    sincosf(TWOPI*py, &s, &c); const float2 Ey = make_float2(c, s);
    sincosf(TWOPI*pz, &s, &c); const float2 Ez = make_float2(c, s);

    // per-lane constants for the recurrence
    const float2 z2  = cmul(Ez, Ez);
    const float2 z4  = cmul(z2, z2);
    const float2 cz5 = conj2(cmul(z4, Ez));            // Ez^-5
    const float2 Cy  = cmul(Ey, cz5);                  // iz wrap, ky+1
    const float2 yy2 = cmul(Ey, Ey);
    const float2 yy4 = cmul(yy2, yy2);
    const float2 yy8 = cmul(yy4, yy4);
    const float2 y11 = cmul(cmul(yy8, yy2), Ey);
    const float2 Cy6 = cmul(conj2(y11), cz5);          // ky 5 -> -6
    const float2 Cx  = cmul(cmul(Ex, Ey), cz5);        // iy wrap, kx+1
    const float2 x3  = cmul(cmul(Ex, Ex), Ex);
    const float2 x6  = cmul(x3, x3);
    // e(m_start): kx for ix=3*c4 in {0,3,-6,-3}
    float2 e = (c4==0) ? make_float2(1.f, 0.f)
             : (c4==1) ? x3
             : (c4==2) ? conj2(x6)
             :           conj2(x3);

    const short* Ab = Abf + (size_t)b*27648 + (((size_t)col*54)*4 + (size_t)c4)*8;
    f32x4 acc = {0.f, 0.f, 0.f, 0.f};

    #pragma unroll 1
    for (int o=0; o<3; ++o){
        if (o) e = cmul(e, Cx);          // m_rel 72o-1 -> 72o
        #pragma unroll
        for (int u=0; u<18; ++u){
            bf16x8 bfr;
            #pragma unroll
            for (int qq=0; qq<4; ++qq){
                const int g = 4*u + qq;               // compile-time, 0..71
                if (g > 0){
                    const bool izstep = (g % 6) != 0;
                    float2 F = izstep ? Ez : (g == 36 ? Cy6 : Cy);
                    e = cmul(e, F);
                }
                bfr[2*qq]   = f2bf(e.x);
                bfr[2*qq+1] = f2bf(e.y);
            }
            bf16x8 afr = *(const bf16x8*)(Ab + (size_t)(o*18 + u)*32);
            acc = __builtin_amdgcn_mfma_f32_16x16x32_bf16(afr, bfr, acc, 0, 0, 0);
        }
    }

    float* yb = y + (size_t)b*CC*NN + n;
    #pragma unroll
    for (int r=0; r<4; ++r){
        const int ch = c4*4 + r;                      // D row = (lane>>4)*4 + reg
        yb[(size_t)ch*NN]        = acc[r];
        yb[(size_t)(31-ch)*NN]   = acc[r];
    }
}

extern "C" void kernel_launch(void* const* d_in, const int* in_sizes, int n_in,
                              void* d_out, int out_size, void* d_ws, size_t ws_size,
                              hipStream_t stream){
    const float* x   = (const float*)d_in[0];
    const float* pos = (const float*)d_in[1];
    const float* w1  = (const float*)d_in[2];
    const float* w2  = (const float*)d_in[3];
    const float* w3  = (const float*)d_in[4];
    const float* w4  = (const float*)d_in[5];
    float* out = (float*)d_out;
    char* wsb = (char*)d_ws;

    // ws layout (bytes):
    float* wt   = (float*)(wsb);                 // 4*216*1024*2*4 = 7,077,888
    float* xft  = (float*)(wsb + 7077888);       // 110592*4      =   442,368
    short* Abf  = (short*)(wsb + 7520256);       // 2*27648*2     =   110,592
    float* part = (float*)(wsb + 7741440);       // 64*110592*4   = 28,311,552 (fwd partials)
    const bool use_part = (ws_size >= 36052992ull);

    wtrans_kernel<<<dim3(216,4), 256, 0, stream>>>(w1, w2, w3, w4, wt);

    if (use_part){
        fwd_kernel<false><<<dim3(NCH,9,2), 128, 0, stream>>>(x, pos, part);
        reduce_kernel<<<dim3(432), 256, 0, stream>>>(part, xft);
    } else {
        hipMemsetAsync(xft, 0, 442368, stream);
        fwd_kernel<true><<<dim3(NCH,9,2), 128, 0, stream>>>(x, pos, xft);
    }

    mix_kernel<<<dim3(108,2), 256, 0, stream>>>(xft, wt, Abf);

    inv_kernel<<<dim3(NN/64, BB), 256, 0, stream>>>(pos, Abf, out);
}

// Round 6
// 54.342 us; speedup vs baseline: 2.9924x; 1.5369x over previous
//
#include <hip/hip_runtime.h>
#include <hip/hip_bf16.h>

#define TWOPI 6.28318530717958647692f

#define BB 2
#define CC 32
#define NN 8192
#define MH 864                      // 12*12*6 retained modes

typedef short bf16x8 __attribute__((ext_vector_type(8)));
typedef float f32x4  __attribute__((ext_vector_type(4)));

__device__ __forceinline__ float2 cmul(float2 a, float2 b){
    return make_float2(fmaf(a.x, b.x, -(a.y*b.y)), fmaf(a.x, b.y, a.y*b.x));
}
__device__ __forceinline__ float2 conj2(float2 a){ return make_float2(a.x, -a.y); }
__device__ __forceinline__ short f2bf(float x){
    __hip_bfloat16 h = __float2bfloat16(x);
    union { __hip_bfloat16 h; short s; } u; u.h = h; return u.s;
}

// ---------------- weight transpose: wt[q][abz][i][o][2] ----------------
__global__ __launch_bounds__(256)
void wtrans_kernel(const float* __restrict__ w1, const float* __restrict__ w2,
                   const float* __restrict__ w3, const float* __restrict__ w4,
                   float* __restrict__ wt){
    const int abz = blockIdx.x;       // 0..215  (a*36 + b*6 + z)
    const int q   = blockIdx.y;       // 0..3
    const float* w = (q==0)?w1:(q==1)?w2:(q==2)?w3:w4;
    const int tid = threadIdx.x;
    #pragma unroll
    for (int k=0;k<4;k++){
        int iop = tid + k*256;        // (i*32+o) in 0..1023
        float2 v = *(const float2*)(w + ((size_t)iop*216 + abz)*2);
        *(float2*)(wt + (((size_t)q*216 + abz)*1024 + iop)*2) = v;
    }
}

// ============ MFMA forward NUFFT ============
// F[b][r][c], r = recurrence row: c4*432 + 2*t + reim, t = (ix%3)*72 + iy*6 + iz,
// c4 = ix/3.  F[2t] = sum_n x[c,n] cos(2pi k.p), F[2t+1] = -sum_n x[c,n] sin(...).
// grid (32 ksplit, 18 mblock, B), block 128 = 2 waves; wave w owns chunk 2*bm+w
// (24 modes = 48 rows = 3 MFMA row-tiles). K-split 32: 256 points per block,
// 2 rounds of 128. Phases staged per-point into mode-major LDS (b16 scatter),
// consumed as plain ds_read_b128 A-fragments.
__global__ __launch_bounds__(128, 2)
void fwd2_kernel(const float* __restrict__ x, const float* __restrict__ pos,
                 float* __restrict__ part){
    const int tid = threadIdx.x;
    const int l   = tid & 63;
    const int w   = tid >> 6;               // wave id (uniform)
    const int ks  = blockIdx.x;             // 0..31
    const int bm  = blockIdx.y;             // 0..17
    const int b   = blockIdx.z;

    __shared__ short P2[6][16][136];        // [chunk-group][mode-row][point], 26112 B
    __shared__ short xl[32][136];           // [c][n] bf16, 8704 B

    f32x4 acc[3][2];
    #pragma unroll
    for (int i=0;i<3;i++)
      #pragma unroll
      for (int j=0;j<2;j++) acc[i][j] = (f32x4){0.f,0.f,0.f,0.f};

    const int kxbase[4] = {0, 3, -6, -3};

    #pragma unroll 1
    for (int rnd=0; rnd<2; ++rnd){
        const int n0 = ks*256 + rnd*128;
        __syncthreads();
        // ---- stage x tile (fp32 -> bf16): 32 c x 128 n
        #pragma unroll
        for (int k2=0;k2<8;k2++){
            int idx = k2*128 + tid;         // float4 index, 0..1023
            int c = idx >> 5;
            int j = idx & 31;
            float4 v = *(const float4*)(x + ((size_t)b*CC + c)*NN + n0 + j*4);
            short4 s4;
            s4.x = f2bf(v.x); s4.y = f2bf(v.y); s4.z = f2bf(v.z); s4.w = f2bf(v.w);
            *(short4*)(&xl[c][j*4]) = s4;
        }
        // ---- stage phases for point p = tid (both chunks)
        {
            const int n = n0 + tid;
            const float px = pos[((size_t)b*NN + n)*3 + 0];
            const float py = pos[((size_t)b*NN + n)*3 + 1];
            const float pz = pos[((size_t)b*NN + n)*3 + 2];
            float s, c;
            sincosf(TWOPI*px, &s, &c); const float2 Exf = make_float2(c, -s);
            sincosf(TWOPI*py, &s, &c); const float2 Eyf = make_float2(c, -s);
            sincosf(TWOPI*pz, &s, &c); const float2 Ezf = make_float2(c, -s);
            const float2 z2  = cmul(Ezf, Ezf);
            const float2 z4  = cmul(z2, z2);
            const float2 czf5 = conj2(cmul(z4, Ezf));       // Ezf^-5
            const float2 Cyf  = cmul(Eyf, czf5);            // ky+1, kz 5->0
            const float2 y2 = cmul(Eyf, Eyf);
            const float2 y4 = cmul(y2, y2);
            const float2 y8 = cmul(y4, y4);
            const float2 y11 = cmul(cmul(y8, y2), Eyf);
            const float2 Cy6f = cmul(conj2(y11), czf5);     // ky 5->-6
            #pragma unroll
            for (int cc=0; cc<2; ++cc){
                const int cid = 2*bm + cc;
                const int c4  = cid/9, lc = cid%9;
                const int kx0 = kxbase[c4] + lc/3;
                const int lm3 = lc%3;
                float2 e = make_float2(1.f, 0.f);
                const int ax = kx0 < 0 ? -kx0 : kx0;
                #pragma unroll
                for (int i2=0;i2<6;i2++) if (i2 < ax) e = cmul(e, Exf);
                if (kx0 < 0) e = conj2(e);
                if (lm3 == 1) e = cmul(e, y4);
                else if (lm3 == 2) e = cmul(e, conj2(y4));
                const float2 F12 = (lm3 == 1) ? Cy6f : Cyf;
                #pragma unroll
                for (int g3=0; g3<3; ++g3){
                    #pragma unroll
                    for (int j=0;j<8;++j){
                        const int gg = g3*8 + j;
                        if (gg){
                            float2 F = (gg % 6) ? Ezf : (gg == 12 ? F12 : Cyf);
                            e = cmul(e, F);
                        }
                        P2[cc*3+g3][2*j  ][tid] = f2bf(e.x);
                        P2[cc*3+g3][2*j+1][tid] = f2bf(e.y);
                    }
                }
            }
        }
        __syncthreads();
        // ---- MFMA: wave w -> groups 3w..3w+2
        #pragma unroll
        for (int kstep=0; kstep<4; ++kstep){
            const int kn = kstep*32 + (l>>4)*8;
            bf16x8 bfr0 = *(const bf16x8*)(&xl[(l&15)     ][kn]);
            bf16x8 bfr1 = *(const bf16x8*)(&xl[(l&15) + 16][kn]);
            #pragma unroll
            for (int g3=0; g3<3; ++g3){
                bf16x8 afr = *(const bf16x8*)(&P2[w*3+g3][l&15][kn]);
                acc[g3][0] = __builtin_amdgcn_mfma_f32_16x16x32_bf16(afr, bfr0, acc[g3][0], 0,0,0);
                acc[g3][1] = __builtin_amdgcn_mfma_f32_16x16x32_bf16(afr, bfr1, acc[g3][1], 0,0,0);
            }
        }
    }
    // ---- store partials: part[ks][b][1728][32]
    const int Rb = (2*bm + w)*48;
    #pragma unroll
    for (int g3=0; g3<3; ++g3)
      #pragma unroll
      for (int nt=0; nt<2; ++nt)
        #pragma unroll
        for (int r=0; r<4; ++r){
            const int R = Rb + g3*16 + (l>>4)*4 + r;
            const int C = (l&15) + nt*16;
            part[(((size_t)ks*BB + b)*1728 + R)*32 + C] = acc[g3][nt][r];
        }
}

// ---------------- split-K reduce (32-way) ----------------
__global__ __launch_bounds__(256)
void reduce2_kernel(const float* __restrict__ part, float* __restrict__ F){
    const int i = blockIdx.x*256 + threadIdx.x;   // 110592 = 432*256
    float s = 0.f;
    #pragma unroll 8
    for (int k=0;k<32;k++) s += part[(size_t)k*110592 + i];
    F[i] = s;
}

// ---------------- atomic fallback forward (writes F layout directly) ----------------
__global__ __launch_bounds__(128, 2)
void fwd_atomic_kernel(const float* __restrict__ x, const float* __restrict__ pos,
                       float* __restrict__ F){
    const int tid = threadIdx.x;
    const int colslot = tid & 15;
    const int cs = tid >> 4;
    const int col = blockIdx.y * 16 + colslot;  // ix*12 + iy
    const int ixm = col / 12;
    const int iym = col % 12;
    const int b   = blockIdx.z;
    const int nb0 = blockIdx.x * 128;

    __shared__ float2 exl[12][65];
    __shared__ float2 eyl[12][65];
    __shared__ float2 ezt[64][8];
    __shared__ float  xl[CC][68];

    float acc[6][4][2];
    #pragma unroll
    for (int z=0;z<6;z++)
      #pragma unroll
      for (int j=0;j<4;j++){ acc[z][j][0]=0.f; acc[z][j][1]=0.f; }

    for (int t=0; t<2; ++t){
        const int nb = nb0 + t*64;
        __syncthreads();
        if (tid < 64){
            const int n = nb + tid;
            const float px = pos[((size_t)b*NN + n)*3 + 0];
            const float py = pos[((size_t)b*NN + n)*3 + 1];
            const float pz = pos[((size_t)b*NN + n)*3 + 2];
            float s, c;
            float2 pw[7];
            sincosf(TWOPI*px, &s, &c);
            { float2 e1 = make_float2(c, -s);
              pw[0] = make_float2(1.f, 0.f);
              #pragma unroll
              for (int k=1;k<7;k++) pw[k] = cmul(pw[k-1], e1);
              #pragma unroll
              for (int k=0;k<6;k++) exl[k][tid] = pw[k];
              #pragma unroll
              for (int k=6;k<12;k++) exl[k][tid] = make_float2(pw[12-k].x, -pw[12-k].y);
            }
            sincosf(TWOPI*py, &s, &c);
            { float2 e1 = make_float2(c, -s);
              pw[0] = make_float2(1.f, 0.f);
              #pragma unroll
              for (int k=1;k<7;k++) pw[k] = cmul(pw[k-1], e1);
              #pragma unroll
              for (int k=0;k<6;k++) eyl[k][tid] = pw[k];
              #pragma unroll
              for (int k=6;k<12;k++) eyl[k][tid] = make_float2(pw[12-k].x, -pw[12-k].y);
            }
            sincosf(TWOPI*pz, &s, &c);
            { float2 e1 = make_float2(c, -s);
              float2 qv = make_float2(1.f, 0.f);
              #pragma unroll
              for (int k=0;k<6;k++){ ezt[tid][k] = qv; qv = cmul(qv, e1); }
            }
        }
        #pragma unroll
        for (int k=0;k<4;k++){
            int v = tid + k*128;
            int c = v >> 4;
            int j = v & 15;
            float4 xv = *(const float4*)(x + (size_t)(b*CC + c)*NN + nb + j*4);
            *(float4*)(&xl[c][j*4]) = xv;
        }
        __syncthreads();

        #pragma unroll 2
        for (int np=0; np<64; ++np){
            float2 rex = exl[ixm][np];
            float2 rey = eyl[iym][np];
            float2 exy = cmul(rex, rey);
            float xv0 = xl[cs*4+0][np];
            float xv1 = xl[cs*4+1][np];
            float xv2 = xl[cs*4+2][np];
            float xv3 = xl[cs*4+3][np];
            const float4* ezp = (const float4*)(&ezt[np][0]);
            float4 ea = ezp[0], eb2 = ezp[1], ec = ezp[2];
            float2 ezv[6];
            ezv[0] = make_float2(ea.x, ea.y);  ezv[1] = make_float2(ea.z, ea.w);
            ezv[2] = make_float2(eb2.x, eb2.y); ezv[3] = make_float2(eb2.z, eb2.w);
            ezv[4] = make_float2(ec.x, ec.y);  ezv[5] = make_float2(ec.z, ec.w);
            #pragma unroll
            for (int z=0; z<6; ++z){
                float2 ph = cmul(exy, ezv[z]);
                acc[z][0][0] = fmaf(ph.x, xv0, acc[z][0][0]);
                acc[z][0][1] = fmaf(ph.y, xv0, acc[z][0][1]);
                acc[z][1][0] = fmaf(ph.x, xv1, acc[z][1][0]);
                acc[z][1][1] = fmaf(ph.y, xv1, acc[z][1][1]);
                acc[z][2][0] = fmaf(ph.x, xv2, acc[z][2][0]);
                acc[z][2][1] = fmaf(ph.y, xv2, acc[z][2][1]);
                acc[z][3][0] = fmaf(ph.x, xv3, acc[z][3][0]);
                acc[z][3][1] = fmaf(ph.y, xv3, acc[z][3][1]);
            }
        }
    }

    const int c0 = cs*4;
    const int c4f = ixm/3;
    const int tb  = (ixm%3)*72 + iym*6;
    #pragma unroll
    for (int z=0;z<6;z++)
      #pragma unroll
      for (int j=0;j<4;j++){
        const int R = c4f*432 + 2*(tb + z);
        float* p = F + ((size_t)b*1728 + R)*32 + c0 + j;
        atomicAdd(p,      acc[z][j][0]);
        atomicAdd(p + 32, acc[z][j][1]);
      }
}

// ---------------- spectral mix + hermitian channel fold -> bf16 A-matrix ----------------
// reads F[b][r][c] (recurrence-row layout), writes Abf for the MFMA inverse.
// grid (108, B), block 256 = 8 modes x 32 out-channels
__global__ __launch_bounds__(256)
void mix_kernel(const float* __restrict__ F, const float* __restrict__ wt,
                short* __restrict__ Abf){
    const int tid = threadIdx.x;
    const int o  = tid & 31;
    const int ml = tid >> 5;      // 0..7
    const int b  = blockIdx.y;
    const int m0 = blockIdx.x * 8;

    __shared__ float xs[512];
    __shared__ float os[8][32][2];

    const float* Fb = F + (size_t)b*55296;
    const int r0 = (m0/216)*432 + 2*(m0%216);
    xs[tid]     = Fb[r0*32 + tid];
    xs[tid+256] = Fb[r0*32 + 256 + tid];
    __syncthreads();

    const int m  = m0 + ml;
    const int ix = m / 72;
    const int iy = (m / 6) % 12;
    const int iz = m % 6;
    const int q  = (ix>=6 ? 1 : 0) + (iy>=6 ? 2 : 0);   // w1,w2,w3,w4
    const int a  = ix % 6;
    const int bb2 = iy % 6;
    const int abz = (a*6 + bb2)*6 + iz;
    const float* wq = wt + ((size_t)q*216 + abz)*2048;

    float orr = 0.f, oii = 0.f;
    #pragma unroll 8
    for (int i=0;i<32;i++){
        float xr = xs[ml*64 + i];
        float xi = xs[ml*64 + 32 + i];
        float2 wv = *(const float2*)(wq + (i*32 + o)*2);
        orr = fmaf(xr, wv.x, orr); orr = fmaf(-xi, wv.y, orr);
        oii = fmaf(xr, wv.y, oii); oii = fmaf( xi, wv.x, oii);
    }
    os[ml][o][0] = orr;
    os[ml][o][1] = oii;
    __syncthreads();
    if (o < 16){
        const float sc2 = 2.0f / (float)NN;
        float tr =  (os[ml][o][0] + os[ml][31-o][0]) * sc2;
        float ti = -((os[ml][o][1] + os[ml][31-o][1]) * sc2);
        const int mc4 = m / 216;
        const int mr  = m % 216;
        const int kk  = mr >> 2;
        const int qq  = mr & 3;
        short2 v; v.x = f2bf(tr); v.y = f2bf(ti);
        *(short2*)(Abf + (size_t)b*27648 + (((size_t)o*54 + kk)*4 + mc4)*8 + 2*qq) = v;
    }
}

// ---------------- inverse NUFFT: MFMA over K=1728 (864 modes x re/im) ----------------
__global__ __launch_bounds__(256)
void inv_kernel(const float* __restrict__ pos, const short* __restrict__ Abf,
                float* __restrict__ y){
    const int tid = threadIdx.x;
    const int l   = tid & 63;
    const int w   = tid >> 6;            // wave 0..3 -> n-tile
    const int col = l & 15;              // B-col (n-offset) AND A-row (channel)
    const int c4  = l >> 4;              // k-slot group
    const int b   = blockIdx.y;
    const int n   = blockIdx.x*64 + w*16 + col;

    const float px = pos[((size_t)b*NN + n)*3 + 0];
    const float py = pos[((size_t)b*NN + n)*3 + 1];
    const float pz = pos[((size_t)b*NN + n)*3 + 2];
    float s, c;
    sincosf(TWOPI*px, &s, &c); const float2 Ex = make_float2(c, s);
    sincosf(TWOPI*py, &s, &c); const float2 Ey = make_float2(c, s);
    sincosf(TWOPI*pz, &s, &c); const float2 Ez = make_float2(c, s);

    const float2 z2  = cmul(Ez, Ez);
    const float2 z4  = cmul(z2, z2);
    const float2 cz5 = conj2(cmul(z4, Ez));            // Ez^-5
    const float2 Cy  = cmul(Ey, cz5);                  // iz wrap, ky+1
    const float2 yy2 = cmul(Ey, Ey);
    const float2 yy4 = cmul(yy2, yy2);
    const float2 yy8 = cmul(yy4, yy4);
    const float2 y11 = cmul(cmul(yy8, yy2), Ey);
    const float2 Cy6 = cmul(conj2(y11), cz5);          // ky 5 -> -6
    const float2 Cx  = cmul(cmul(Ex, Ey), cz5);        // iy wrap, kx+1
    const float2 x3  = cmul(cmul(Ex, Ex), Ex);
    const float2 x6  = cmul(x3, x3);
    float2 e = (c4==0) ? make_float2(1.f, 0.f)
             : (c4==1) ? x3
             : (c4==2) ? conj2(x6)
             :           conj2(x3);

    const short* Ab = Abf + (size_t)b*27648 + (((size_t)col*54)*4 + (size_t)c4)*8;
    f32x4 acc = {0.f, 0.f, 0.f, 0.f};

    #pragma unroll 1
    for (int o=0; o<3; ++o){
        if (o) e = cmul(e, Cx);
        #pragma unroll
        for (int u=0; u<18; ++u){
            bf16x8 bfr;
            #pragma unroll
            for (int qq=0; qq<4; ++qq){
                const int g = 4*u + qq;               // 0..71
                if (g > 0){
                    const bool izstep = (g % 6) != 0;
                    float2 F = izstep ? Ez : (g == 36 ? Cy6 : Cy);
                    e = cmul(e, F);
                }
                bfr[2*qq]   = f2bf(e.x);
                bfr[2*qq+1] = f2bf(e.y);
            }
            bf16x8 afr = *(const bf16x8*)(Ab + (size_t)(o*18 + u)*32);
            acc = __builtin_amdgcn_mfma_f32_16x16x32_bf16(afr, bfr, acc, 0, 0, 0);
        }
    }

    float* yb = y + (size_t)b*CC*NN + n;
    #pragma unroll
    for (int r=0; r<4; ++r){
        const int ch = c4*4 + r;
        yb[(size_t)ch*NN]        = acc[r];
        yb[(size_t)(31-ch)*NN]   = acc[r];
    }
}

extern "C" void kernel_launch(void* const* d_in, const int* in_sizes, int n_in,
                              void* d_out, int out_size, void* d_ws, size_t ws_size,
                              hipStream_t stream){
    const float* x   = (const float*)d_in[0];
    const float* pos = (const float*)d_in[1];
    const float* w1  = (const float*)d_in[2];
    const float* w2  = (const float*)d_in[3];
    const float* w3  = (const float*)d_in[4];
    const float* w4  = (const float*)d_in[5];
    float* out = (float*)d_out;
    char* wsb = (char*)d_ws;

    // ws layout (bytes):
    float* wt    = (float*)(wsb);                // 4*216*1024*2*4 = 7,077,888
    float* F     = (float*)(wsb + 7077888);      // 2*1728*32*4   =   442,368
    short* Abf   = (short*)(wsb + 7520256);      // 2*27648*2     =   110,592
    float* part2 = (float*)(wsb + 7741440);      // 32*110592*4   = 14,155,776
    const bool use_part = (ws_size >= 21897216ull);

    wtrans_kernel<<<dim3(216,4), 256, 0, stream>>>(w1, w2, w3, w4, wt);

    if (use_part){
        fwd2_kernel<<<dim3(32,18,2), 128, 0, stream>>>(x, pos, part2);
        reduce2_kernel<<<dim3(432), 256, 0, stream>>>(part2, F);
    } else {
        hipMemsetAsync(F, 0, 442368, stream);
        fwd_atomic_kernel<<<dim3(64,9,2), 128, 0, stream>>>(x, pos, F);
    }

    mix_kernel<<<dim3(108,2), 256, 0, stream>>>(F, wt, Abf);

    inv_kernel<<<dim3(NN/64, BB), 256, 0, stream>>>(pos, Abf, out);
}

// Round 7
// 45.048 us; speedup vs baseline: 3.6098x; 1.2063x over previous
//
#include <hip/hip_runtime.h>
#include <hip/hip_bf16.h>

#define TWOPI 6.28318530717958647692f

#define BB 2
#define CC 32
#define NN 8192
#define MH 864                      // 12*12*6 retained modes

typedef short bf16x8 __attribute__((ext_vector_type(8)));
typedef float f32x4  __attribute__((ext_vector_type(4)));

__device__ __forceinline__ float2 cmul(float2 a, float2 b){
    return make_float2(fmaf(a.x, b.x, -(a.y*b.y)), fmaf(a.x, b.y, a.y*b.x));
}
__device__ __forceinline__ float2 conj2(float2 a){ return make_float2(a.x, -a.y); }
__device__ __forceinline__ short f2bf(float x){
    __hip_bfloat16 h = __float2bfloat16(x);
    union { __hip_bfloat16 h; short s; } u; u.h = h; return u.s;
}

// ---------------- weight transpose: wt[q][abz][i][o][2] ----------------
__global__ __launch_bounds__(256)
void wtrans_kernel(const float* __restrict__ w1, const float* __restrict__ w2,
                   const float* __restrict__ w3, const float* __restrict__ w4,
                   float* __restrict__ wt){
    const int abz = blockIdx.x;       // 0..215  (a*36 + b*6 + z)
    const int q   = blockIdx.y;       // 0..3
    const float* w = (q==0)?w1:(q==1)?w2:(q==2)?w3:w4;
    const int tid = threadIdx.x;
    #pragma unroll
    for (int k=0;k<4;k++){
        int iop = tid + k*256;        // (i*32+o) in 0..1023
        float2 v = *(const float2*)(w + ((size_t)iop*216 + abz)*2);
        *(float2*)(wt + (((size_t)q*216 + abz)*1024 + iop)*2) = v;
    }
}

// ============ MFMA forward NUFFT ============
// part[ks][b][r][c], r = recurrence row: c4*432 + 2*t + reim,
// t = (ix%3)*72 + iy*6 + iz, c4 = ix/3.
// grid (32 ksplit, 18 mblock, B), block 128 = 2 waves.
__global__ __launch_bounds__(128, 2)
void fwd2_kernel(const float* __restrict__ x, const float* __restrict__ pos,
                 float* __restrict__ part){
    const int tid = threadIdx.x;
    const int l   = tid & 63;
    const int w   = tid >> 6;               // wave id (uniform)
    const int ks  = blockIdx.x;             // 0..31
    const int bm  = blockIdx.y;             // 0..17
    const int b   = blockIdx.z;

    __shared__ short P2[6][16][136];        // [chunk-group][mode-row][point], 26112 B
    __shared__ short xl[32][136];           // [c][n] bf16, 8704 B

    f32x4 acc[3][2];
    #pragma unroll
    for (int i=0;i<3;i++)
      #pragma unroll
      for (int j=0;j<2;j++) acc[i][j] = (f32x4){0.f,0.f,0.f,0.f};

    const int kxbase[4] = {0, 3, -6, -3};

    #pragma unroll 1
    for (int rnd=0; rnd<2; ++rnd){
        const int n0 = ks*256 + rnd*128;
        __syncthreads();
        // ---- stage x tile (fp32 -> bf16): 32 c x 128 n
        #pragma unroll
        for (int k2=0;k2<8;k2++){
            int idx = k2*128 + tid;         // float4 index, 0..1023
            int c = idx >> 5;
            int j = idx & 31;
            float4 v = *(const float4*)(x + ((size_t)b*CC + c)*NN + n0 + j*4);
            short4 s4;
            s4.x = f2bf(v.x); s4.y = f2bf(v.y); s4.z = f2bf(v.z); s4.w = f2bf(v.w);
            *(short4*)(&xl[c][j*4]) = s4;
        }
        // ---- stage phases for point p = tid (both chunks)
        {
            const int n = n0 + tid;
            const float px = pos[((size_t)b*NN + n)*3 + 0];
            const float py = pos[((size_t)b*NN + n)*3 + 1];
            const float pz = pos[((size_t)b*NN + n)*3 + 2];
            float s, c;
            sincosf(TWOPI*px, &s, &c); const float2 Exf = make_float2(c, -s);
            sincosf(TWOPI*py, &s, &c); const float2 Eyf = make_float2(c, -s);
            sincosf(TWOPI*pz, &s, &c); const float2 Ezf = make_float2(c, -s);
            const float2 z2  = cmul(Ezf, Ezf);
            const float2 z4  = cmul(z2, z2);
            const float2 czf5 = conj2(cmul(z4, Ezf));       // Ezf^-5
            const float2 Cyf  = cmul(Eyf, czf5);            // ky+1, kz 5->0
            const float2 y2 = cmul(Eyf, Eyf);
            const float2 y4 = cmul(y2, y2);
            const float2 y8 = cmul(y4, y4);
            const float2 y11 = cmul(cmul(y8, y2), Eyf);
            const float2 Cy6f = cmul(conj2(y11), czf5);     // ky 5->-6
            #pragma unroll
            for (int cc=0; cc<2; ++cc){
                const int cid = 2*bm + cc;
                const int c4  = cid/9, lc = cid%9;
                const int kx0 = kxbase[c4] + lc/3;
                const int lm3 = lc%3;
                float2 e = make_float2(1.f, 0.f);
                const int ax = kx0 < 0 ? -kx0 : kx0;
                #pragma unroll
                for (int i2=0;i2<6;i2++) if (i2 < ax) e = cmul(e, Exf);
                if (kx0 < 0) e = conj2(e);
                if (lm3 == 1) e = cmul(e, y4);
                else if (lm3 == 2) e = cmul(e, conj2(y4));
                const float2 F12 = (lm3 == 1) ? Cy6f : Cyf;
                #pragma unroll
                for (int g3=0; g3<3; ++g3){
                    #pragma unroll
                    for (int j=0;j<8;++j){
                        const int gg = g3*8 + j;
                        if (gg){
                            float2 F = (gg % 6) ? Ezf : (gg == 12 ? F12 : Cyf);
                            e = cmul(e, F);
                        }
                        P2[cc*3+g3][2*j  ][tid] = f2bf(e.x);
                        P2[cc*3+g3][2*j+1][tid] = f2bf(e.y);
                    }
                }
            }
        }
        __syncthreads();
        // ---- MFMA: wave w -> groups 3w..3w+2
        #pragma unroll
        for (int kstep=0; kstep<4; ++kstep){
            const int kn = kstep*32 + (l>>4)*8;
            bf16x8 bfr0 = *(const bf16x8*)(&xl[(l&15)     ][kn]);
            bf16x8 bfr1 = *(const bf16x8*)(&xl[(l&15) + 16][kn]);
            #pragma unroll
            for (int g3=0; g3<3; ++g3){
                bf16x8 afr = *(const bf16x8*)(&P2[w*3+g3][l&15][kn]);
                acc[g3][0] = __builtin_amdgcn_mfma_f32_16x16x32_bf16(afr, bfr0, acc[g3][0], 0,0,0);
                acc[g3][1] = __builtin_amdgcn_mfma_f32_16x16x32_bf16(afr, bfr1, acc[g3][1], 0,0,0);
            }
        }
    }
    // ---- store partials: part[ks][b][1728][32]
    const int Rb = (2*bm + w)*48;
    #pragma unroll
    for (int g3=0; g3<3; ++g3)
      #pragma unroll
      for (int nt=0; nt<2; ++nt)
        #pragma unroll
        for (int r=0; r<4; ++r){
            const int R = Rb + g3*16 + (l>>4)*4 + r;
            const int C = (l&15) + nt*16;
            part[(((size_t)ks*BB + b)*1728 + R)*32 + C] = acc[g3][nt][r];
        }
}

// ---------------- atomic fallback forward (writes part chunk-0 layout) ----------------
__global__ __launch_bounds__(128, 2)
void fwd_atomic_kernel(const float* __restrict__ x, const float* __restrict__ pos,
                       float* __restrict__ F){
    const int tid = threadIdx.x;
    const int colslot = tid & 15;
    const int cs = tid >> 4;
    const int col = blockIdx.y * 16 + colslot;  // ix*12 + iy
    const int ixm = col / 12;
    const int iym = col % 12;
    const int b   = blockIdx.z;
    const int nb0 = blockIdx.x * 128;

    __shared__ float2 exl[12][65];
    __shared__ float2 eyl[12][65];
    __shared__ float2 ezt[64][8];
    __shared__ float  xl[CC][68];

    float acc[6][4][2];
    #pragma unroll
    for (int z=0;z<6;z++)
      #pragma unroll
      for (int j=0;j<4;j++){ acc[z][j][0]=0.f; acc[z][j][1]=0.f; }

    for (int t=0; t<2; ++t){
        const int nb = nb0 + t*64;
        __syncthreads();
        if (tid < 64){
            const int n = nb + tid;
            const float px = pos[((size_t)b*NN + n)*3 + 0];
            const float py = pos[((size_t)b*NN + n)*3 + 1];
            const float pz = pos[((size_t)b*NN + n)*3 + 2];
            float s, c;
            float2 pw[7];
            sincosf(TWOPI*px, &s, &c);
            { float2 e1 = make_float2(c, -s);
              pw[0] = make_float2(1.f, 0.f);
              #pragma unroll
              for (int k=1;k<7;k++) pw[k] = cmul(pw[k-1], e1);
              #pragma unroll
              for (int k=0;k<6;k++) exl[k][tid] = pw[k];
              #pragma unroll
              for (int k=6;k<12;k++) exl[k][tid] = make_float2(pw[12-k].x, -pw[12-k].y);
            }
            sincosf(TWOPI*py, &s, &c);
            { float2 e1 = make_float2(c, -s);
              pw[0] = make_float2(1.f, 0.f);
              #pragma unroll
              for (int k=1;k<7;k++) pw[k] = cmul(pw[k-1], e1);
              #pragma unroll
              for (int k=0;k<6;k++) eyl[k][tid] = pw[k];
              #pragma unroll
              for (int k=6;k<12;k++) eyl[k][tid] = make_float2(pw[12-k].x, -pw[12-k].y);
            }
            sincosf(TWOPI*pz, &s, &c);
            { float2 e1 = make_float2(c, -s);
              float2 qv = make_float2(1.f, 0.f);
              #pragma unroll
              for (int k=0;k<6;k++){ ezt[tid][k] = qv; qv = cmul(qv, e1); }
            }
        }
        #pragma unroll
        for (int k=0;k<4;k++){
            int v = tid + k*128;
            int c = v >> 4;
            int j = v & 15;
            float4 xv = *(const float4*)(x + (size_t)(b*CC + c)*NN + nb + j*4);
            *(float4*)(&xl[c][j*4]) = xv;
        }
        __syncthreads();

        #pragma unroll 2
        for (int np=0; np<64; ++np){
            float2 rex = exl[ixm][np];
            float2 rey = eyl[iym][np];
            float2 exy = cmul(rex, rey);
            float xv0 = xl[cs*4+0][np];
            float xv1 = xl[cs*4+1][np];
            float xv2 = xl[cs*4+2][np];
            float xv3 = xl[cs*4+3][np];
            const float4* ezp = (const float4*)(&ezt[np][0]);
            float4 ea = ezp[0], eb2 = ezp[1], ec = ezp[2];
            float2 ezv[6];
            ezv[0] = make_float2(ea.x, ea.y);  ezv[1] = make_float2(ea.z, ea.w);
            ezv[2] = make_float2(eb2.x, eb2.y); ezv[3] = make_float2(eb2.z, eb2.w);
            ezv[4] = make_float2(ec.x, ec.y);  ezv[5] = make_float2(ec.z, ec.w);
            #pragma unroll
            for (int z=0; z<6; ++z){
                float2 ph = cmul(exy, ezv[z]);
                acc[z][0][0] = fmaf(ph.x, xv0, acc[z][0][0]);
                acc[z][0][1] = fmaf(ph.y, xv0, acc[z][0][1]);
                acc[z][1][0] = fmaf(ph.x, xv1, acc[z][1][0]);
                acc[z][1][1] = fmaf(ph.y, xv1, acc[z][1][1]);
                acc[z][2][0] = fmaf(ph.x, xv2, acc[z][2][0]);
                acc[z][2][1] = fmaf(ph.y, xv2, acc[z][2][1]);
                acc[z][3][0] = fmaf(ph.x, xv3, acc[z][3][0]);
                acc[z][3][1] = fmaf(ph.y, xv3, acc[z][3][1]);
            }
        }
    }

    const int c0 = cs*4;
    const int c4f = ixm/3;
    const int tb  = (ixm%3)*72 + iym*6;
    #pragma unroll
    for (int z=0;z<6;z++)
      #pragma unroll
      for (int j=0;j<4;j++){
        const int R = c4f*432 + 2*(tb + z);
        float* p = F + ((size_t)b*1728 + R)*32 + c0 + j;
        atomicAdd(p,      acc[z][j][0]);
        atomicAdd(p + 32, acc[z][j][1]);
      }
}

// ---------------- fused split-K reduce + spectral mix + channel fold -> bf16 A ----------------
// reads part[ks][b][1728][32], writes Abf for the MFMA inverse.
// grid (216, B), block 128 = 4 modes x 32 out-channels
template<int NK>
__global__ __launch_bounds__(128)
void mix_kernel(const float* __restrict__ part, const float* __restrict__ wt,
                short* __restrict__ Abf){
    const int tid = threadIdx.x;
    const int o  = tid & 31;
    const int ml = tid >> 5;      // 0..3
    const int b  = blockIdx.y;
    const int m0 = blockIdx.x * 4;

    __shared__ float xs[256];
    __shared__ float os[4][32][2];

    // fused 32-way split-K reduce of rows r0..r0+7 (256 floats)
    const int r0 = (m0/216)*432 + 2*(m0%216);
    {
        const float* pb = part + (((size_t)b*1728 + r0)*32) + 2*tid;
        float s0 = 0.f, s1 = 0.f;
        #pragma unroll 8
        for (int k=0;k<NK;k++){
            float2 v = *(const float2*)(pb + (size_t)k*110592);
            s0 += v.x; s1 += v.y;
        }
        xs[2*tid]   = s0;
        xs[2*tid+1] = s1;
    }
    __syncthreads();

    const int m  = m0 + ml;
    const int ix = m / 72;
    const int iy = (m / 6) % 12;
    const int iz = m % 6;
    const int q  = (ix>=6 ? 1 : 0) + (iy>=6 ? 2 : 0);   // w1,w2,w3,w4
    const int a  = ix % 6;
    const int bb2 = iy % 6;
    const int abz = (a*6 + bb2)*6 + iz;
    const float* wq = wt + ((size_t)q*216 + abz)*2048;

    float orr = 0.f, oii = 0.f;
    #pragma unroll 8
    for (int i=0;i<32;i++){
        float xr = xs[ml*64 + i];
        float xi = xs[ml*64 + 32 + i];
        float2 wv = *(const float2*)(wq + (i*32 + o)*2);
        orr = fmaf(xr, wv.x, orr); orr = fmaf(-xi, wv.y, orr);
        oii = fmaf(xr, wv.y, oii); oii = fmaf( xi, wv.x, oii);
    }
    os[ml][o][0] = orr;
    os[ml][o][1] = oii;
    __syncthreads();
    if (o < 16){
        const float sc2 = 2.0f / (float)NN;
        float tr =  (os[ml][o][0] + os[ml][31-o][0]) * sc2;
        float ti = -((os[ml][o][1] + os[ml][31-o][1]) * sc2);
        const int mc4 = m / 216;
        const int mr  = m % 216;
        const int kk  = mr >> 2;
        const int qq  = mr & 3;
        short2 v; v.x = f2bf(tr); v.y = f2bf(ti);
        *(short2*)(Abf + (size_t)b*27648 + (((size_t)o*54 + kk)*4 + mc4)*8 + 2*qq) = v;
    }
}

// ---------------- inverse NUFFT: MFMA, 12-wave blocks (3 o-groups x 4 n-tiles) ----------------
// y[b][c][n] = y[b][31-c][n] = sum_k A[k][c] * P[k][n]; o-group og covers modes
// m_rel in [72*og, 72*og+72): e-start = base(c4) * Ex^og.  LDS-reduce over og.
__global__ __launch_bounds__(768)
void inv_kernel(const float* __restrict__ pos, const short* __restrict__ Abf,
                float* __restrict__ y){
    const int tid = threadIdx.x;
    const int og  = tid >> 8;            // 0..2  (o-group)
    const int w4  = (tid >> 6) & 3;      // n-tile within block
    const int l   = tid & 63;
    const int col = l & 15;              // B-col (n-offset) AND A-row (channel)
    const int c4  = l >> 4;              // k-slot group
    const int b   = blockIdx.y;
    const int n   = blockIdx.x*64 + w4*16 + col;

    __shared__ float red[2][4][16][17];  // [og-1][w4][c][ncol], padded

    const float px = pos[((size_t)b*NN + n)*3 + 0];
    const float py = pos[((size_t)b*NN + n)*3 + 1];
    const float pz = pos[((size_t)b*NN + n)*3 + 2];
    float s, c;
    sincosf(TWOPI*px, &s, &c); const float2 Ex = make_float2(c, s);
    sincosf(TWOPI*py, &s, &c); const float2 Ey = make_float2(c, s);
    sincosf(TWOPI*pz, &s, &c); const float2 Ez = make_float2(c, s);

    const float2 z2  = cmul(Ez, Ez);
    const float2 z4  = cmul(z2, z2);
    const float2 cz5 = conj2(cmul(z4, Ez));            // Ez^-5
    const float2 Cy  = cmul(Ey, cz5);                  // iz wrap, ky+1
    const float2 yy2 = cmul(Ey, Ey);
    const float2 yy4 = cmul(yy2, yy2);
    const float2 yy8 = cmul(yy4, yy4);
    const float2 y11 = cmul(cmul(yy8, yy2), Ey);
    const float2 Cy6 = cmul(conj2(y11), cz5);          // ky 5 -> -6
    const float2 x3  = cmul(cmul(Ex, Ex), Ex);
    const float2 x6  = cmul(x3, x3);
    float2 e = (c4==0) ? make_float2(1.f, 0.f)
             : (c4==1) ? x3
             : (c4==2) ? conj2(x6)
             :           conj2(x3);
    if (og >= 1) e = cmul(e, Ex);        // o-group start: kx += og
    if (og == 2) e = cmul(e, Ex);

    const short* Ab = Abf + (size_t)b*27648 + (((size_t)col*54)*4 + (size_t)c4)*8
                          + (size_t)og*18*32;
    f32x4 acc = {0.f, 0.f, 0.f, 0.f};

    #pragma unroll
    for (int u=0; u<18; ++u){
        bf16x8 bfr;
        #pragma unroll
        for (int qq=0; qq<4; ++qq){
            const int g = 4*u + qq;               // 0..71 within o-group
            if (g > 0){
                const bool izstep = (g % 6) != 0;
                float2 F = izstep ? Ez : (g == 36 ? Cy6 : Cy);
                e = cmul(e, F);
            }
            bfr[2*qq]   = f2bf(e.x);
            bfr[2*qq+1] = f2bf(e.y);
        }
        bf16x8 afr = *(const bf16x8*)(Ab + (size_t)u*32);
        acc = __builtin_amdgcn_mfma_f32_16x16x32_bf16(afr, bfr, acc, 0, 0, 0);
    }

    if (og >= 1){
        #pragma unroll
        for (int r=0; r<4; ++r) red[og-1][w4][c4*4 + r][col] = acc[r];
    }
    __syncthreads();
    if (og == 0){
        float* yb = y + (size_t)b*CC*NN + n;
        #pragma unroll
        for (int r=0; r<4; ++r){
            const int ch = c4*4 + r;
            float v = acc[r] + red[0][w4][ch][col] + red[1][w4][ch][col];
            yb[(size_t)ch*NN]      = v;
            yb[(size_t)(31-ch)*NN] = v;
        }
    }
}

extern "C" void kernel_launch(void* const* d_in, const int* in_sizes, int n_in,
                              void* d_out, int out_size, void* d_ws, size_t ws_size,
                              hipStream_t stream){
    const float* x   = (const float*)d_in[0];
    const float* pos = (const float*)d_in[1];
    const float* w1  = (const float*)d_in[2];
    const float* w2  = (const float*)d_in[3];
    const float* w3  = (const float*)d_in[4];
    const float* w4  = (const float*)d_in[5];
    float* out = (float*)d_out;
    char* wsb = (char*)d_ws;

    // ws layout (bytes):
    float* wt    = (float*)(wsb);                // 4*216*1024*2*4 = 7,077,888
    short* Abf   = (short*)(wsb + 7520256);      // 2*27648*2     =   110,592
    float* part2 = (float*)(wsb + 7741440);      // 32*110592*4   = 14,155,776
    const bool use_part = (ws_size >= 21897216ull);

    wtrans_kernel<<<dim3(216,4), 256, 0, stream>>>(w1, w2, w3, w4, wt);

    if (use_part){
        fwd2_kernel<<<dim3(32,18,2), 128, 0, stream>>>(x, pos, part2);
        mix_kernel<32><<<dim3(216,2), 128, 0, stream>>>(part2, wt, Abf);
    } else {
        hipMemsetAsync(part2, 0, 442368, stream);
        fwd_atomic_kernel<<<dim3(64,9,2), 128, 0, stream>>>(x, pos, part2);
        mix_kernel<1><<<dim3(216,2), 128, 0, stream>>>(part2, wt, Abf);
    }

    inv_kernel<<<dim3(NN/64, BB), 768, 0, stream>>>(pos, Abf, out);
}

// Round 8
// 37.197 us; speedup vs baseline: 4.3716x; 1.2111x over previous
//
#include <hip/hip_runtime.h>

#define TWOPI 6.28318530717958647692f

#define BB 2
#define CC 32
#define NN 8192

typedef short bf16x8 __attribute__((ext_vector_type(8)));
typedef float f32x4  __attribute__((ext_vector_type(4)));

__device__ __forceinline__ float2 cmul(float2 a, float2 b){
    return make_float2(fmaf(a.x, b.x, -(a.y*b.y)), fmaf(a.x, b.y, a.y*b.x));
}
__device__ __forceinline__ float2 conj2(float2 a){ return make_float2(a.x, -a.y); }
// RNE float->bf16 (finite data only; avoids libdevice call)
__device__ __forceinline__ short f2bf(float x){
    union { float f; unsigned u; } v; v.f = x;
    unsigned r = v.u + (0x7fffu + ((v.u >> 16) & 1u));
    return (short)(r >> 16);
}

// ---------------- standalone weight transpose (fallback path only) ----------------
__global__ __launch_bounds__(256)
void wtrans_kernel(const float* __restrict__ w1, const float* __restrict__ w2,
                   const float* __restrict__ w3, const float* __restrict__ w4,
                   float* __restrict__ wt){
    const int abz = blockIdx.x;
    const int q   = blockIdx.y;
    const float* w = (q==0)?w1:(q==1)?w2:(q==2)?w3:w4;
    const int tid = threadIdx.x;
    #pragma unroll
    for (int k=0;k<4;k++){
        int iop = tid + k*256;
        float2 v = *(const float2*)(w + ((size_t)iop*216 + abz)*2);
        *(float2*)(wt + (((size_t)q*216 + abz)*1024 + iop)*2) = v;
    }
}

// ============ fused: MFMA forward NUFFT (blocks 0..575) + wtrans (576..1439) ============
// part[ks][b][r][c], r = recurrence row: c4*432 + 2*t + reim,
// t = (ix%3)*72 + iy*6 + iz, c4 = ix/3.
// fwd2 role: 256 thr = 4 waves; wave w owns chunk cid=4*bm+w (24 modes = 48 rows);
// 4 rounds x 64 points; phases via ky-ladder (segment advance = Ey; 5-deep Ez chains).
__global__ __launch_bounds__(256, 4)
void fused_fwd_kernel(const float* __restrict__ x, const float* __restrict__ pos,
                      const float* __restrict__ w1, const float* __restrict__ w2,
                      const float* __restrict__ w3, const float* __restrict__ w4,
                      float* __restrict__ wt, float* __restrict__ part){
    __shared__ short  P2[12][16][72];   // [group][mode-row][point]  27,648 B
    __shared__ short  xl[32][72];       // [c][point] bf16            4,608 B
    __shared__ float2 el[3][64];        // per-axis unit phases       1,536 B

    const int bid = blockIdx.x;
    const int tid = threadIdx.x;

    if (bid >= 576){
        // ---- wtrans role ----
        const int wid = bid - 576;
        const int abz = wid % 216;
        const int q   = wid / 216;
        const float* w = (q==0)?w1:(q==1)?w2:(q==2)?w3:w4;
        #pragma unroll
        for (int k=0;k<4;k++){
            int iop = tid + k*256;
            float2 v = *(const float2*)(w + ((size_t)iop*216 + abz)*2);
            *(float2*)(wt + (((size_t)q*216 + abz)*1024 + iop)*2) = v;
        }
        return;
    }

    // ---- fwd2 role ----
    const int ks  = bid & 31;            // 0..31
    const int bm  = (bid >> 5) % 9;      // 0..8
    const int b   = bid / 288;           // 0..1
    const int l   = tid & 63;
    const int w   = tid >> 6;            // wave 0..3
    const int cid = 4*bm + w;            // chunk 0..35 (wave-uniform)
    const int c4k = cid / 9;
    const int lc  = cid % 9;
    const int kxb = (c4k==0) ? 0 : (c4k==1) ? 3 : (c4k==2) ? -6 : -3;
    const int kx0 = kxb + lc/3;
    const int lm3 = lc % 3;

    f32x4 acc[3][2];
    #pragma unroll
    for (int i=0;i<3;i++)
      #pragma unroll
      for (int j=0;j<2;j++) acc[i][j] = (f32x4){0.f,0.f,0.f,0.f};

    #pragma unroll 1
    for (int rnd=0; rnd<4; ++rnd){
        const int n0 = ks*256 + rnd*64;
        __syncthreads();
        // stage x tile (fp32 -> bf16): 32 c x 64 n
        #pragma unroll
        for (int k=0;k<2;k++){
            int idx = k*256 + tid;       // float4 index 0..511
            int c = idx >> 4;
            int j = idx & 15;
            float4 v = *(const float4*)(x + ((size_t)b*CC + c)*NN + n0 + j*4);
            short4 s4;
            s4.x = f2bf(v.x); s4.y = f2bf(v.y); s4.z = f2bf(v.z); s4.w = f2bf(v.w);
            *(short4*)(&xl[c][j*4]) = s4;
        }
        // stage per-axis unit phases (forward sign: exp(-i*2pi*p))
        if (tid < 192){
            const int axis = tid >> 6;
            const int p    = tid & 63;
            float pc = pos[((size_t)b*NN + n0 + p)*3 + axis];
            float s, c;
            sincosf(TWOPI*pc, &s, &c);
            el[axis][p] = make_float2(c, -s);
        }
        __syncthreads();
        // phase-gen: wave w stages chunk cid for point l (ky-ladder)
        {
            const float2 Exf = el[0][l];
            const float2 Eyf = el[1][l];
            const float2 Ezf = el[2][l];
            float2 e = make_float2(1.f, 0.f);
            const int ax = kx0 < 0 ? -kx0 : kx0;
            #pragma unroll
            for (int i2=0;i2<6;i2++) if (i2 < ax) e = cmul(e, Exf);
            if (kx0 < 0) e = conj2(e);
            const float2 y2  = cmul(Eyf, Eyf);
            const float2 y4  = cmul(y2, y2);
            if      (lm3 == 1) e = cmul(e, y4);
            else if (lm3 == 2) e = cmul(e, conj2(y4));
            const float2 y8  = cmul(y4, y4);
            const float2 y11 = cmul(cmul(y8, y2), Eyf);
            float2 Sv[4];
            Sv[0] = e;
            Sv[1] = cmul(Sv[0], Eyf);
            Sv[2] = cmul(Sv[1], (lm3==1) ? conj2(y11) : Eyf);
            Sv[3] = cmul(Sv[2], Eyf);
            #pragma unroll
            for (int s=0; s<4; ++s){
                float2 ee = Sv[s];
                #pragma unroll
                for (int kz=0; kz<6; ++kz){
                    const int g  = 6*s + kz;       // 0..23
                    const int g3 = g >> 3;
                    const int j  = g & 7;
                    P2[w*3+g3][2*j  ][l] = f2bf(ee.x);
                    P2[w*3+g3][2*j+1][l] = f2bf(ee.y);
                    if (kz < 5) ee = cmul(ee, Ezf);
                }
            }
        }
        __syncthreads();
        // MFMA: 2 ksteps x 3 groups x 2 channel-halves
        #pragma unroll
        for (int kstep=0; kstep<2; ++kstep){
            const int kn = kstep*32 + (l>>4)*8;
            bf16x8 bfr0 = *(const bf16x8*)(&xl[(l&15)     ][kn]);
            bf16x8 bfr1 = *(const bf16x8*)(&xl[(l&15) + 16][kn]);
            #pragma unroll
            for (int g3=0; g3<3; ++g3){
                bf16x8 afr = *(const bf16x8*)(&P2[w*3+g3][l&15][kn]);
                acc[g3][0] = __builtin_amdgcn_mfma_f32_16x16x32_bf16(afr, bfr0, acc[g3][0],0,0,0);
                acc[g3][1] = __builtin_amdgcn_mfma_f32_16x16x32_bf16(afr, bfr1, acc[g3][1],0,0,0);
            }
        }
    }
    // store partials: part[ks][b][1728][32]
    const int Rb = cid*48;
    #pragma unroll
    for (int g3=0; g3<3; ++g3)
      #pragma unroll
      for (int nt=0; nt<2; ++nt)
        #pragma unroll
        for (int r=0; r<4; ++r){
            const int R = Rb + g3*16 + (l>>4)*4 + r;
            const int C = (l&15) + nt*16;
            part[(((size_t)ks*BB + b)*1728 + R)*32 + C] = acc[g3][nt][r];
        }
}

// ---------------- atomic fallback forward (writes part chunk-0 layout) ----------------
__global__ __launch_bounds__(128, 2)
void fwd_atomic_kernel(const float* __restrict__ x, const float* __restrict__ pos,
                       float* __restrict__ F){
    const int tid = threadIdx.x;
    const int colslot = tid & 15;
    const int cs = tid >> 4;
    const int col = blockIdx.y * 16 + colslot;  // ix*12 + iy
    const int ixm = col / 12;
    const int iym = col % 12;
    const int b   = blockIdx.z;
    const int nb0 = blockIdx.x * 128;

    __shared__ float2 exl[12][65];
    __shared__ float2 eyl[12][65];
    __shared__ float2 ezt[64][8];
    __shared__ float  xl[CC][68];

    float acc[6][4][2];
    #pragma unroll
    for (int z=0;z<6;z++)
      #pragma unroll
      for (int j=0;j<4;j++){ acc[z][j][0]=0.f; acc[z][j][1]=0.f; }

    for (int t=0; t<2; ++t){
        const int nb = nb0 + t*64;
        __syncthreads();
        if (tid < 64){
            const int n = nb + tid;
            const float px = pos[((size_t)b*NN + n)*3 + 0];
            const float py = pos[((size_t)b*NN + n)*3 + 1];
            const float pz = pos[((size_t)b*NN + n)*3 + 2];
            float s, c;
            float2 pw[7];
            sincosf(TWOPI*px, &s, &c);
            { float2 e1 = make_float2(c, -s);
              pw[0] = make_float2(1.f, 0.f);
              #pragma unroll
              for (int k=1;k<7;k++) pw[k] = cmul(pw[k-1], e1);
              #pragma unroll
              for (int k=0;k<6;k++) exl[k][tid] = pw[k];
              #pragma unroll
              for (int k=6;k<12;k++) exl[k][tid] = make_float2(pw[12-k].x, -pw[12-k].y);
            }
            sincosf(TWOPI*py, &s, &c);
            { float2 e1 = make_float2(c, -s);
              pw[0] = make_float2(1.f, 0.f);
              #pragma unroll
              for (int k=1;k<7;k++) pw[k] = cmul(pw[k-1], e1);
              #pragma unroll
              for (int k=0;k<6;k++) eyl[k][tid] = pw[k];
              #pragma unroll
              for (int k=6;k<12;k++) eyl[k][tid] = make_float2(pw[12-k].x, -pw[12-k].y);
            }
            sincosf(TWOPI*pz, &s, &c);
            { float2 e1 = make_float2(c, -s);
              float2 qv = make_float2(1.f, 0.f);
              #pragma unroll
              for (int k=0;k<6;k++){ ezt[tid][k] = qv; qv = cmul(qv, e1); }
            }
        }
        #pragma unroll
        for (int k=0;k<4;k++){
            int v = tid + k*128;
            int c = v >> 4;
            int j = v & 15;
            float4 xv = *(const float4*)(x + (size_t)(b*CC + c)*NN + nb + j*4);
            *(float4*)(&xl[c][j*4]) = xv;
        }
        __syncthreads();

        #pragma unroll 2
        for (int np=0; np<64; ++np){
            float2 rex = exl[ixm][np];
            float2 rey = eyl[iym][np];
            float2 exy = cmul(rex, rey);
            float xv0 = xl[cs*4+0][np];
            float xv1 = xl[cs*4+1][np];
            float xv2 = xl[cs*4+2][np];
            float xv3 = xl[cs*4+3][np];
            const float4* ezp = (const float4*)(&ezt[np][0]);
            float4 ea = ezp[0], eb2 = ezp[1], ec = ezp[2];
            float2 ezv[6];
            ezv[0] = make_float2(ea.x, ea.y);  ezv[1] = make_float2(ea.z, ea.w);
            ezv[2] = make_float2(eb2.x, eb2.y); ezv[3] = make_float2(eb2.z, eb2.w);
            ezv[4] = make_float2(ec.x, ec.y);  ezv[5] = make_float2(ec.z, ec.w);
            #pragma unroll
            for (int z=0; z<6; ++z){
                float2 ph = cmul(exy, ezv[z]);
                acc[z][0][0] = fmaf(ph.x, xv0, acc[z][0][0]);
                acc[z][0][1] = fmaf(ph.y, xv0, acc[z][0][1]);
                acc[z][1][0] = fmaf(ph.x, xv1, acc[z][1][0]);
                acc[z][1][1] = fmaf(ph.y, xv1, acc[z][1][1]);
                acc[z][2][0] = fmaf(ph.x, xv2, acc[z][2][0]);
                acc[z][2][1] = fmaf(ph.y, xv2, acc[z][2][1]);
                acc[z][3][0] = fmaf(ph.x, xv3, acc[z][3][0]);
                acc[z][3][1] = fmaf(ph.y, xv3, acc[z][3][1]);
            }
        }
    }

    const int c0 = cs*4;
    const int c4f = ixm/3;
    const int tb  = (ixm%3)*72 + iym*6;
    #pragma unroll
    for (int z=0;z<6;z++)
      #pragma unroll
      for (int j=0;j<4;j++){
        const int R = c4f*432 + 2*(tb + z);
        float* p = F + ((size_t)b*1728 + R)*32 + c0 + j;
        atomicAdd(p,      acc[z][j][0]);
        atomicAdd(p + 32, acc[z][j][1]);
      }
}

// ---------------- fused split-K reduce + spectral mix + channel fold -> bf16 A ----------------
// grid (216, B), block 128 = 4 modes x 32 out-channels
template<int NK>
__global__ __launch_bounds__(128)
void mix_kernel(const float* __restrict__ part, const float* __restrict__ wt,
                short* __restrict__ Abf){
    const int tid = threadIdx.x;
    const int o  = tid & 31;
    const int ml = tid >> 5;      // 0..3
    const int b  = blockIdx.y;
    const int m0 = blockIdx.x * 4;

    __shared__ float xs[256];
    __shared__ float os[4][32][2];

    const int r0 = (m0/216)*432 + 2*(m0%216);
    {
        const float* pb = part + (((size_t)b*1728 + r0)*32) + 2*tid;
        float s0 = 0.f, s1 = 0.f;
        #pragma unroll 8
        for (int k=0;k<NK;k++){
            float2 v = *(const float2*)(pb + (size_t)k*110592);
            s0 += v.x; s1 += v.y;
        }
        xs[2*tid]   = s0;
        xs[2*tid+1] = s1;
    }
    __syncthreads();

    const int m  = m0 + ml;
    const int ix = m / 72;
    const int iy = (m / 6) % 12;
    const int iz = m % 6;
    const int q  = (ix>=6 ? 1 : 0) + (iy>=6 ? 2 : 0);
    const int a  = ix % 6;
    const int bb2 = iy % 6;
    const int abz = (a*6 + bb2)*6 + iz;
    const float* wq = wt + ((size_t)q*216 + abz)*2048;

    float orr = 0.f, oii = 0.f;
    #pragma unroll 8
    for (int i=0;i<32;i++){
        float xr = xs[ml*64 + i];
        float xi = xs[ml*64 + 32 + i];
        float2 wv = *(const float2*)(wq + (i*32 + o)*2);
        orr = fmaf(xr, wv.x, orr); orr = fmaf(-xi, wv.y, orr);
        oii = fmaf(xr, wv.y, oii); oii = fmaf( xi, wv.x, oii);
    }
    os[ml][o][0] = orr;
    os[ml][o][1] = oii;
    __syncthreads();
    if (o < 16){
        const float sc2 = 2.0f / (float)NN;
        float tr =  (os[ml][o][0] + os[ml][31-o][0]) * sc2;
        float ti = -((os[ml][o][1] + os[ml][31-o][1]) * sc2);
        const int mc4 = m / 216;
        const int mr  = m % 216;
        const int kk  = mr >> 2;
        const int qq  = mr & 3;
        short2 v; v.x = f2bf(tr); v.y = f2bf(ti);
        *(short2*)(Abf + (size_t)b*27648 + (((size_t)o*54 + kk)*4 + mc4)*8 + 2*qq) = v;
    }
}

// ---------------- inverse NUFFT: MFMA, 12-wave blocks, ky-ladder phases ----------------
__global__ __launch_bounds__(768)
void inv_kernel(const float* __restrict__ pos, const short* __restrict__ Abf,
                float* __restrict__ y){
    const int tid = threadIdx.x;
    const int og  = tid >> 8;            // 0..2  (o-group)
    const int w4  = (tid >> 6) & 3;      // n-tile within block
    const int l   = tid & 63;
    const int col = l & 15;
    const int c4  = l >> 4;
    const int b   = blockIdx.y;
    const int n   = blockIdx.x*64 + w4*16 + col;

    __shared__ float red[2][4][16][17];

    const float px = pos[((size_t)b*NN + n)*3 + 0];
    const float py = pos[((size_t)b*NN + n)*3 + 1];
    const float pz = pos[((size_t)b*NN + n)*3 + 2];
    float s, c;
    sincosf(TWOPI*px, &s, &c); const float2 Ex = make_float2(c, s);
    sincosf(TWOPI*py, &s, &c); const float2 Ey = make_float2(c, s);
    sincosf(TWOPI*pz, &s, &c); const float2 Ez = make_float2(c, s);

    const float2 yy2 = cmul(Ey, Ey);
    const float2 yy4 = cmul(yy2, yy2);
    const float2 yy8 = cmul(yy4, yy4);
    const float2 cj11 = conj2(cmul(cmul(yy8, yy2), Ey));   // Ey^-11
    const float2 x3  = cmul(cmul(Ex, Ex), Ex);
    const float2 x6  = cmul(x3, x3);
    float2 e = (c4==0) ? make_float2(1.f, 0.f)
             : (c4==1) ? x3
             : (c4==2) ? conj2(x6)
             :           conj2(x3);
    if (og >= 1) e = cmul(e, Ex);        // o-group start: kx += og
    if (og == 2) e = cmul(e, Ex);

    const short* Ab = Abf + (size_t)b*27648 + (((size_t)col*54)*4 + (size_t)c4)*8
                          + (size_t)og*18*32;
    f32x4 acc = {0.f, 0.f, 0.f, 0.f};

    // ky-ladder: segment advance S *= Ey (or Ey^-11 at the 5->-6 wrap), 5-deep Ez chains
    float2 S  = e;
    float2 ee = S;
    #pragma unroll
    for (int u=0; u<18; ++u){
        bf16x8 bfr;
        #pragma unroll
        for (int qq=0; qq<4; ++qq){
            const int g = 4*u + qq;               // 0..71 within o-group
            if (g > 0){
                if (g % 6) ee = cmul(ee, Ez);
                else { S = cmul(S, (g==36) ? cj11 : Ey); ee = S; }
            }
            bfr[2*qq]   = f2bf(ee.x);
            bfr[2*qq+1] = f2bf(ee.y);
        }
        bf16x8 afr = *(const bf16x8*)(Ab + (size_t)u*32);
        acc = __builtin_amdgcn_mfma_f32_16x16x32_bf16(afr, bfr, acc, 0, 0, 0);
    }

    if (og >= 1){
        #pragma unroll
        for (int r=0; r<4; ++r) red[og-1][w4][c4*4 + r][col] = acc[r];
    }
    __syncthreads();
    if (og == 0){
        float* yb = y + (size_t)b*CC*NN + n;
        #pragma unroll
        for (int r=0; r<4; ++r){
            const int ch = c4*4 + r;
            float v = acc[r] + red[0][w4][ch][col] + red[1][w4][ch][col];
            yb[(size_t)ch*NN]      = v;
            yb[(size_t)(31-ch)*NN] = v;
        }
    }
}

extern "C" void kernel_launch(void* const* d_in, const int* in_sizes, int n_in,
                              void* d_out, int out_size, void* d_ws, size_t ws_size,
                              hipStream_t stream){
    const float* x   = (const float*)d_in[0];
    const float* pos = (const float*)d_in[1];
    const float* w1  = (const float*)d_in[2];
    const float* w2  = (const float*)d_in[3];
    const float* w3  = (const float*)d_in[4];
    const float* w4  = (const float*)d_in[5];
    float* out = (float*)d_out;
    char* wsb = (char*)d_ws;

    // ws layout (bytes):
    float* wt    = (float*)(wsb);                // 4*216*1024*2*4 = 7,077,888
    short* Abf   = (short*)(wsb + 7520256);      // 2*27648*2     =   110,592
    float* part2 = (float*)(wsb + 7741440);      // 32*110592*4   = 14,155,776
    const bool use_part = (ws_size >= 21897216ull);

    if (use_part){
        fused_fwd_kernel<<<dim3(1440), 256, 0, stream>>>(x, pos, w1, w2, w3, w4, wt, part2);
        mix_kernel<32><<<dim3(216,2), 128, 0, stream>>>(part2, wt, Abf);
    } else {
        wtrans_kernel<<<dim3(216,4), 256, 0, stream>>>(w1, w2, w3, w4, wt);
        hipMemsetAsync(part2, 0, 442368, stream);
        fwd_atomic_kernel<<<dim3(64,9,2), 128, 0, stream>>>(x, pos, part2);
        mix_kernel<1><<<dim3(216,2), 128, 0, stream>>>(part2, wt, Abf);
    }

    inv_kernel<<<dim3(NN/64, BB), 768, 0, stream>>>(pos, Abf, out);
}

// Round 9
// 36.033 us; speedup vs baseline: 4.5128x; 1.0323x over previous
//
#include <hip/hip_runtime.h>

#define TWOPI 6.28318530717958647692f

#define BB 2
#define CC 32
#define NN 8192

typedef short bf16x8 __attribute__((ext_vector_type(8)));
typedef float f32x4  __attribute__((ext_vector_type(4)));

__device__ __forceinline__ float2 cmul(float2 a, float2 b){
    return make_float2(fmaf(a.x, b.x, -(a.y*b.y)), fmaf(a.x, b.y, a.y*b.x));
}
__device__ __forceinline__ float2 conj2(float2 a){ return make_float2(a.x, -a.y); }
// 1-instr packed f32x2 -> bf16x2 (RNE), T12 recipe
__device__ __forceinline__ unsigned pk_bf16(float lo, float hi){
    unsigned r;
    asm("v_cvt_pk_bf16_f32 %0, %1, %2" : "=v"(r) : "v"(lo), "v"(hi));
    return r;
}
// HW sin/cos take REVOLUTIONS; valid since pos in [0,1)
__device__ __forceinline__ float hw_sin(float p){
    float r; asm("v_sin_f32 %0, %1" : "=v"(r) : "v"(p)); return r;
}
__device__ __forceinline__ float hw_cos(float p){
    float r; asm("v_cos_f32 %0, %1" : "=v"(r) : "v"(p)); return r;
}
// scalar fallback (fallback kernels only)
__device__ __forceinline__ short f2bf(float x){
    union { float f; unsigned u; } v; v.f = x;
    unsigned r = v.u + (0x7fffu + ((v.u >> 16) & 1u));
    return (short)(r >> 16);
}

// ---------------- standalone weight transpose (fallback path only) ----------------
__global__ __launch_bounds__(256)
void wtrans_kernel(const float* __restrict__ w1, const float* __restrict__ w2,
                   const float* __restrict__ w3, const float* __restrict__ w4,
                   float* __restrict__ wt){
    const int abz = blockIdx.x;
    const int q   = blockIdx.y;
    const float* w = (q==0)?w1:(q==1)?w2:(q==2)?w3:w4;
    const int tid = threadIdx.x;
    #pragma unroll
    for (int k=0;k<4;k++){
        int iop = tid + k*256;
        float2 v = *(const float2*)(w + ((size_t)iop*216 + abz)*2);
        *(float2*)(wt + (((size_t)q*216 + abz)*1024 + iop)*2) = v;
    }
}

// ============ fused: MFMA forward NUFFT (blocks 0..575) + wtrans (576..1439) ============
// part[ks][b][r][c], r = recurrence row: c4*432 + 2*t + reim,
// t = (ix%3)*72 + iy*6 + iz, c4 = ix/3.
// 256 thr = 4 waves; wave w owns chunk cid=4*bm+w (24 modes = 48 rows);
// 4 rounds x 64 points; per-lane hw sin/cos; ky-ladder; pk'd bf16 stores.
__global__ __launch_bounds__(256, 4)
void fused_fwd_kernel(const float* __restrict__ x, const float* __restrict__ pos,
                      const float* __restrict__ w1, const float* __restrict__ w2,
                      const float* __restrict__ w3, const float* __restrict__ w4,
                      float* __restrict__ wt, float* __restrict__ part){
    __shared__ short  P2[12][16][72];   // [group][mode-row][point]  27,648 B
    __shared__ short  xl[32][72];       // [c][point] bf16            4,608 B

    const int bid = blockIdx.x;
    const int tid = threadIdx.x;

    if (bid >= 576){
        // ---- wtrans role ----
        const int wid = bid - 576;
        const int abz = wid % 216;
        const int q   = wid / 216;
        const float* w = (q==0)?w1:(q==1)?w2:(q==2)?w3:w4;
        #pragma unroll
        for (int k=0;k<4;k++){
            int iop = tid + k*256;
            float2 v = *(const float2*)(w + ((size_t)iop*216 + abz)*2);
            *(float2*)(wt + (((size_t)q*216 + abz)*1024 + iop)*2) = v;
        }
        return;
    }

    // ---- fwd role ----
    const int ks  = bid & 31;            // 0..31
    const int bm  = (bid >> 5) % 9;      // 0..8
    const int b   = bid / 288;           // 0..1
    const int l   = tid & 63;
    const int w   = tid >> 6;            // wave 0..3
    const int cid = 4*bm + w;            // chunk 0..35 (wave-uniform)
    const int c4k = cid / 9;
    const int lc  = cid % 9;
    const int kxb = (c4k==0) ? 0 : (c4k==1) ? 3 : (c4k==2) ? -6 : -3;
    const int kx0 = kxb + lc/3;
    const int lm3 = lc % 3;

    f32x4 acc[3][2];
    #pragma unroll
    for (int i=0;i<3;i++)
      #pragma unroll
      for (int j=0;j<2;j++) acc[i][j] = (f32x4){0.f,0.f,0.f,0.f};

    #pragma unroll 1
    for (int rnd=0; rnd<4; ++rnd){
        const int n0 = ks*256 + rnd*64;
        __syncthreads();
        // stage x tile (fp32 -> bf16, packed): 32 c x 64 n
        #pragma unroll
        for (int k=0;k<2;k++){
            int idx = k*256 + tid;       // float4 index 0..511
            int c = idx >> 4;
            int j = idx & 15;
            float4 v = *(const float4*)(x + ((size_t)b*CC + c)*NN + n0 + j*4);
            unsigned p0 = pk_bf16(v.x, v.y);
            unsigned p1 = pk_bf16(v.z, v.w);
            *(uint2*)(&xl[c][j*4]) = make_uint2(p0, p1);
        }
        // phase-gen: wave w stages chunk cid for point l (ky-ladder, per-lane hw trig)
        {
            const int n = n0 + l;
            const float px = pos[((size_t)b*NN + n)*3 + 0];
            const float py = pos[((size_t)b*NN + n)*3 + 1];
            const float pz = pos[((size_t)b*NN + n)*3 + 2];
            const float2 Exf = make_float2(hw_cos(px), -hw_sin(px));   // exp(-i*2pi*px)
            const float2 Eyf = make_float2(hw_cos(py), -hw_sin(py));
            const float2 Ezf = make_float2(hw_cos(pz), -hw_sin(pz));
            float2 e = make_float2(1.f, 0.f);
            const int ax = kx0 < 0 ? -kx0 : kx0;
            #pragma unroll
            for (int i2=0;i2<6;i2++) if (i2 < ax) e = cmul(e, Exf);
            if (kx0 < 0) e = conj2(e);
            const float2 y2  = cmul(Eyf, Eyf);
            const float2 y4  = cmul(y2, y2);
            if      (lm3 == 1) e = cmul(e, y4);
            else if (lm3 == 2) e = cmul(e, conj2(y4));
            const float2 y8  = cmul(y4, y4);
            const float2 y11 = cmul(cmul(y8, y2), Eyf);
            float2 Sv[4];
            Sv[0] = e;
            Sv[1] = cmul(Sv[0], Eyf);
            Sv[2] = cmul(Sv[1], (lm3==1) ? conj2(y11) : Eyf);
            Sv[3] = cmul(Sv[2], Eyf);
            #pragma unroll
            for (int s2=0; s2<4; ++s2){
                float2 ee = Sv[s2];
                #pragma unroll
                for (int kz=0; kz<6; ++kz){
                    const int g  = 6*s2 + kz;      // 0..23
                    const int g3 = g >> 3;
                    const int j  = g & 7;
                    unsigned pv = pk_bf16(ee.x, ee.y);
                    P2[w*3+g3][2*j  ][l] = (short)(pv & 0xffffu);
                    P2[w*3+g3][2*j+1][l] = (short)(pv >> 16);
                    if (kz < 5) ee = cmul(ee, Ezf);
                }
            }
        }
        __syncthreads();
        // MFMA: 2 ksteps x 3 groups x 2 channel-halves
        #pragma unroll
        for (int kstep=0; kstep<2; ++kstep){
            const int kn = kstep*32 + (l>>4)*8;
            bf16x8 bfr0 = *(const bf16x8*)(&xl[(l&15)     ][kn]);
            bf16x8 bfr1 = *(const bf16x8*)(&xl[(l&15) + 16][kn]);
            #pragma unroll
            for (int g3=0; g3<3; ++g3){
                bf16x8 afr = *(const bf16x8*)(&P2[w*3+g3][l&15][kn]);
                acc[g3][0] = __builtin_amdgcn_mfma_f32_16x16x32_bf16(afr, bfr0, acc[g3][0],0,0,0);
                acc[g3][1] = __builtin_amdgcn_mfma_f32_16x16x32_bf16(afr, bfr1, acc[g3][1],0,0,0);
            }
        }
    }
    // store partials: part[ks][b][1728][32]
    const int Rb = cid*48;
    #pragma unroll
    for (int g3=0; g3<3; ++g3)
      #pragma unroll
      for (int nt=0; nt<2; ++nt)
        #pragma unroll
        for (int r=0; r<4; ++r){
            const int R = Rb + g3*16 + (l>>4)*4 + r;
            const int C = (l&15) + nt*16;
            part[(((size_t)ks*BB + b)*1728 + R)*32 + C] = acc[g3][nt][r];
        }
}

// ---------------- atomic fallback forward (writes part chunk-0 layout) ----------------
__global__ __launch_bounds__(128, 2)
void fwd_atomic_kernel(const float* __restrict__ x, const float* __restrict__ pos,
                       float* __restrict__ F){
    const int tid = threadIdx.x;
    const int colslot = tid & 15;
    const int cs = tid >> 4;
    const int col = blockIdx.y * 16 + colslot;  // ix*12 + iy
    const int ixm = col / 12;
    const int iym = col % 12;
    const int b   = blockIdx.z;
    const int nb0 = blockIdx.x * 128;

    __shared__ float2 exl[12][65];
    __shared__ float2 eyl[12][65];
    __shared__ float2 ezt[64][8];
    __shared__ float  xl[CC][68];

    float acc[6][4][2];
    #pragma unroll
    for (int z=0;z<6;z++)
      #pragma unroll
      for (int j=0;j<4;j++){ acc[z][j][0]=0.f; acc[z][j][1]=0.f; }

    for (int t=0; t<2; ++t){
        const int nb = nb0 + t*64;
        __syncthreads();
        if (tid < 64){
            const int n = nb + tid;
            const float px = pos[((size_t)b*NN + n)*3 + 0];
            const float py = pos[((size_t)b*NN + n)*3 + 1];
            const float pz = pos[((size_t)b*NN + n)*3 + 2];
            float s, c;
            float2 pw[7];
            s = hw_sin(px); c = hw_cos(px);
            { float2 e1 = make_float2(c, -s);
              pw[0] = make_float2(1.f, 0.f);
              #pragma unroll
              for (int k=1;k<7;k++) pw[k] = cmul(pw[k-1], e1);
              #pragma unroll
              for (int k=0;k<6;k++) exl[k][tid] = pw[k];
              #pragma unroll
              for (int k=6;k<12;k++) exl[k][tid] = make_float2(pw[12-k].x, -pw[12-k].y);
            }
            s = hw_sin(py); c = hw_cos(py);
            { float2 e1 = make_float2(c, -s);
              pw[0] = make_float2(1.f, 0.f);
              #pragma unroll
              for (int k=1;k<7;k++) pw[k] = cmul(pw[k-1], e1);
              #pragma unroll
              for (int k=0;k<6;k++) eyl[k][tid] = pw[k];
              #pragma unroll
              for (int k=6;k<12;k++) eyl[k][tid] = make_float2(pw[12-k].x, -pw[12-k].y);
            }
            s = hw_sin(pz); c = hw_cos(pz);
            { float2 e1 = make_float2(c, -s);
              float2 qv = make_float2(1.f, 0.f);
              #pragma unroll
              for (int k=0;k<6;k++){ ezt[tid][k] = qv; qv = cmul(qv, e1); }
            }
        }
        #pragma unroll
        for (int k=0;k<4;k++){
            int v = tid + k*128;
            int c = v >> 4;
            int j = v & 15;
            float4 xv = *(const float4*)(x + (size_t)(b*CC + c)*NN + nb + j*4);
            *(float4*)(&xl[c][j*4]) = xv;
        }
        __syncthreads();

        #pragma unroll 2
        for (int np=0; np<64; ++np){
            float2 rex = exl[ixm][np];
            float2 rey = eyl[iym][np];
            float2 exy = cmul(rex, rey);
            float xv0 = xl[cs*4+0][np];
            float xv1 = xl[cs*4+1][np];
            float xv2 = xl[cs*4+2][np];
            float xv3 = xl[cs*4+3][np];
            const float4* ezp = (const float4*)(&ezt[np][0]);
            float4 ea = ezp[0], eb2 = ezp[1], ec = ezp[2];
            float2 ezv[6];
            ezv[0] = make_float2(ea.x, ea.y);  ezv[1] = make_float2(ea.z, ea.w);
            ezv[2] = make_float2(eb2.x, eb2.y); ezv[3] = make_float2(eb2.z, eb2.w);
            ezv[4] = make_float2(ec.x, ec.y);  ezv[5] = make_float2(ec.z, ec.w);
            #pragma unroll
            for (int z=0; z<6; ++z){
                float2 ph = cmul(exy, ezv[z]);
                acc[z][0][0] = fmaf(ph.x, xv0, acc[z][0][0]);
                acc[z][0][1] = fmaf(ph.y, xv0, acc[z][0][1]);
                acc[z][1][0] = fmaf(ph.x, xv1, acc[z][1][0]);
                acc[z][1][1] = fmaf(ph.y, xv1, acc[z][1][1]);
                acc[z][2][0] = fmaf(ph.x, xv2, acc[z][2][0]);
                acc[z][2][1] = fmaf(ph.y, xv2, acc[z][2][1]);
                acc[z][3][0] = fmaf(ph.x, xv3, acc[z][3][0]);
                acc[z][3][1] = fmaf(ph.y, xv3, acc[z][3][1]);
            }
        }
    }

    const int c0 = cs*4;
    const int c4f = ixm/3;
    const int tb  = (ixm%3)*72 + iym*6;
    #pragma unroll
    for (int z=0;z<6;z++)
      #pragma unroll
      for (int j=0;j<4;j++){
        const int R = c4f*432 + 2*(tb + z);
        float* p = F + ((size_t)b*1728 + R)*32 + c0 + j;
        atomicAdd(p,      acc[z][j][0]);
        atomicAdd(p + 32, acc[z][j][1]);
      }
}

// ---------------- fused split-K reduce + spectral mix + channel fold -> bf16 A ----------------
// grid (216, B), block 128 = 4 modes x 32 out-channels
template<int NK>
__global__ __launch_bounds__(128)
void mix_kernel(const float* __restrict__ part, const float* __restrict__ wt,
                short* __restrict__ Abf){
    const int tid = threadIdx.x;
    const int o  = tid & 31;
    const int ml = tid >> 5;      // 0..3
    const int b  = blockIdx.y;
    const int m0 = blockIdx.x * 4;

    __shared__ float xs[256];
    __shared__ float os[4][32][2];

    const int r0 = (m0/216)*432 + 2*(m0%216);
    {
        const float* pb = part + (((size_t)b*1728 + r0)*32) + 2*tid;
        float s0 = 0.f, s1 = 0.f;
        #pragma unroll 8
        for (int k=0;k<NK;k++){
            float2 v = *(const float2*)(pb + (size_t)k*110592);
            s0 += v.x; s1 += v.y;
        }
        xs[2*tid]   = s0;
        xs[2*tid+1] = s1;
    }
    __syncthreads();

    const int m  = m0 + ml;
    const int ix = m / 72;
    const int iy = (m / 6) % 12;
    const int iz = m % 6;
    const int q  = (ix>=6 ? 1 : 0) + (iy>=6 ? 2 : 0);
    const int a  = ix % 6;
    const int bb2 = iy % 6;
    const int abz = (a*6 + bb2)*6 + iz;
    const float* wq = wt + ((size_t)q*216 + abz)*2048;

    float orr = 0.f, oii = 0.f;
    #pragma unroll 8
    for (int i=0;i<32;i++){
        float xr = xs[ml*64 + i];
        float xi = xs[ml*64 + 32 + i];
        float2 wv = *(const float2*)(wq + (i*32 + o)*2);
        orr = fmaf(xr, wv.x, orr); orr = fmaf(-xi, wv.y, orr);
        oii = fmaf(xr, wv.y, oii); oii = fmaf( xi, wv.x, oii);
    }
    os[ml][o][0] = orr;
    os[ml][o][1] = oii;
    __syncthreads();
    if (o < 16){
        const float sc2 = 2.0f / (float)NN;
        float tr =  (os[ml][o][0] + os[ml][31-o][0]) * sc2;
        float ti = -((os[ml][o][1] + os[ml][31-o][1]) * sc2);
        const int mc4 = m / 216;
        const int mr  = m % 216;
        const int kk  = mr >> 2;
        const int qq  = mr & 3;
        unsigned pv = pk_bf16(tr, ti);
        *(unsigned*)(Abf + (size_t)b*27648 + (((size_t)o*54 + kk)*4 + mc4)*8 + 2*qq) = pv;
    }
}

// ---------------- inverse NUFFT: MFMA, 12-wave blocks, ky-ladder phases ----------------
__global__ __launch_bounds__(768)
void inv_kernel(const float* __restrict__ pos, const short* __restrict__ Abf,
                float* __restrict__ y){
    const int tid = threadIdx.x;
    const int og  = tid >> 8;            // 0..2  (o-group)
    const int w4  = (tid >> 6) & 3;      // n-tile within block
    const int l   = tid & 63;
    const int col = l & 15;
    const int c4  = l >> 4;
    const int b   = blockIdx.y;
    const int n   = blockIdx.x*64 + w4*16 + col;

    __shared__ float red[2][4][16][17];

    const float px = pos[((size_t)b*NN + n)*3 + 0];
    const float py = pos[((size_t)b*NN + n)*3 + 1];
    const float pz = pos[((size_t)b*NN + n)*3 + 2];
    const float2 Ex = make_float2(hw_cos(px), hw_sin(px));   // exp(+i*2pi*px)
    const float2 Ey = make_float2(hw_cos(py), hw_sin(py));
    const float2 Ez = make_float2(hw_cos(pz), hw_sin(pz));

    const float2 yy2 = cmul(Ey, Ey);
    const float2 yy4 = cmul(yy2, yy2);
    const float2 yy8 = cmul(yy4, yy4);
    const float2 cj11 = conj2(cmul(cmul(yy8, yy2), Ey));   // Ey^-11
    const float2 x3  = cmul(cmul(Ex, Ex), Ex);
    const float2 x6  = cmul(x3, x3);
    float2 e = (c4==0) ? make_float2(1.f, 0.f)
             : (c4==1) ? x3
             : (c4==2) ? conj2(x6)
             :           conj2(x3);
    if (og >= 1) e = cmul(e, Ex);        // o-group start: kx += og
    if (og == 2) e = cmul(e, Ex);

    const short* Ab = Abf + (size_t)b*27648 + (((size_t)col*54)*4 + (size_t)c4)*8
                          + (size_t)og*18*32;
    f32x4 acc = {0.f, 0.f, 0.f, 0.f};

    union BU { unsigned u[4]; bf16x8 v; };

    // ky-ladder: segment advance S *= Ey (or Ey^-11 at the 5->-6 wrap), 5-deep Ez chains
    float2 S  = e;
    float2 ee = S;
    #pragma unroll
    for (int u2=0; u2<18; ++u2){
        BU bu;
        #pragma unroll
        for (int qq=0; qq<4; ++qq){
            const int g = 4*u2 + qq;              // 0..71 within o-group
            if (g > 0){
                if (g % 6) ee = cmul(ee, Ez);
                else { S = cmul(S, (g==36) ? cj11 : Ey); ee = S; }
            }
            bu.u[qq] = pk_bf16(ee.x, ee.y);
        }
        bf16x8 afr = *(const bf16x8*)(Ab + (size_t)u2*32);
        acc = __builtin_amdgcn_mfma_f32_16x16x32_bf16(afr, bu.v, acc, 0, 0, 0);
    }

    if (og >= 1){
        #pragma unroll
        for (int r=0; r<4; ++r) red[og-1][w4][c4*4 + r][col] = acc[r];
    }
    __syncthreads();
    if (og == 0){
        float* yb = y + (size_t)b*CC*NN + n;
        #pragma unroll
        for (int r=0; r<4; ++r){
            const int ch = c4*4 + r;
            float v = acc[r] + red[0][w4][ch][col] + red[1][w4][ch][col];
            yb[(size_t)ch*NN]      = v;
            yb[(size_t)(31-ch)*NN] = v;
        }
    }
}

extern "C" void kernel_launch(void* const* d_in, const int* in_sizes, int n_in,
                              void* d_out, int out_size, void* d_ws, size_t ws_size,
                              hipStream_t stream){
    const float* x   = (const float*)d_in[0];
    const float* pos = (const float*)d_in[1];
    const float* w1  = (const float*)d_in[2];
    const float* w2  = (const float*)d_in[3];
    const float* w3  = (const float*)d_in[4];
    const float* w4  = (const float*)d_in[5];
    float* out = (float*)d_out;
    char* wsb = (char*)d_ws;

    // ws layout (bytes):
    float* wt    = (float*)(wsb);                // 4*216*1024*2*4 = 7,077,888
    short* Abf   = (short*)(wsb + 7520256);      // 2*27648*2     =   110,592
    float* part2 = (float*)(wsb + 7741440);      // 32*110592*4   = 14,155,776
    const bool use_part = (ws_size >= 21897216ull);

    if (use_part){
        fused_fwd_kernel<<<dim3(1440), 256, 0, stream>>>(x, pos, w1, w2, w3, w4, wt, part2);
        mix_kernel<32><<<dim3(216,2), 128, 0, stream>>>(part2, wt, Abf);
    } else {
        wtrans_kernel<<<dim3(216,4), 256, 0, stream>>>(w1, w2, w3, w4, wt);
        hipMemsetAsync(part2, 0, 442368, stream);
        fwd_atomic_kernel<<<dim3(64,9,2), 128, 0, stream>>>(x, pos, part2);
        mix_kernel<1><<<dim3(216,2), 128, 0, stream>>>(part2, wt, Abf);
    }

    inv_kernel<<<dim3(NN/64, BB), 768, 0, stream>>>(pos, Abf, out);
}